// Round 6
// baseline (6998.256 us; speedup 1.0000x reference)
//
#include <hip/hip_runtime.h>
#include <hip/hip_bf16.h>

#define NA_ 4096
#define NB_ 4096
#define NN_ 8192            // total nodes
#define EE_ 131072          // edges per direction
#define NE_ (2*EE_ + NN_)   // homogeneous edges incl. self loops = 270336
#define HH_ 512
#define NEG_SLOPE_ 0.2f

// ---------------- float-order <-> unsigned-order mapping for atomic max ----
__device__ inline unsigned fkey(float f) {
    unsigned b = __float_as_uint(f);
    return (b & 0x80000000u) ? ~b : (b | 0x80000000u);
}
__device__ inline float finv(unsigned k) {
    return (k & 0x80000000u) ? __uint_as_float(k & 0x7fffffffu)
                             : __uint_as_float(~k);
}

// ---------------- homogeneous edge id -> (src, dst) ------------------------
// reference: src = [eAB[0], eBA[0]+na, loops], dst = [eAB[1]+na, eBA[1], loops]
__device__ inline void edge_sd(int i, const int* __restrict__ eAB,
                               const int* __restrict__ eBA, int& s, int& d) {
    if (i < EE_)            { s = eAB[i];            d = eAB[EE_ + i] + NA_; }
    else if (i < 2 * EE_)   { int j = i - EE_; s = eBA[j] + NA_; d = eBA[EE_ + j]; }
    else                    { s = i - 2 * EE_;       d = s; }
}

// ---------------- GEMM: C[M,N] = A[M,K] @ op(B) + bias ---------------------
// BT=true : B is [N,K] row-major (C = A @ B^T) -- x@W.T and q@k.T
// BT=false: B is [K,N] row-major (C = A @ B)   -- P@V
template<bool BT>
__global__ __launch_bounds__(256) void gemm_k(
    const float* __restrict__ A, const float* __restrict__ B,
    const float* __restrict__ bias, float* __restrict__ C,
    int M, int N, int K, int lda, int ldb, int ldc)
{
    __shared__ float sA[16][129];
    __shared__ float sB[16][129];
    const int t  = threadIdx.x;
    const int tx = t & 15, ty = t >> 4;
    const int bm = blockIdx.y * 128, bn = blockIdx.x * 128;

    float acc[8][8] = {{0.f}};

    const int lr = t >> 1;          // 0..127
    const int lk = (t & 1) * 8;     // 0 or 8
    const float* Ap = A + (size_t)(bm + lr) * lda + lk;
    const float* BpT = B + (size_t)(bn + lr) * ldb + lk;            // BT path
    const int bkr = t >> 4;         // 0..15   (NN path)
    const int bn8 = (t & 15) * 8;   // 0..120
    const float* BpN = B + (size_t)bkr * ldb + bn + bn8;            // NN path

    for (int k0 = 0; k0 < K; k0 += 16) {
        float4 a0 = *(const float4*)(Ap + k0);
        float4 a1 = *(const float4*)(Ap + k0 + 4);
        float4 b0, b1;
        if (BT) {
            b0 = *(const float4*)(BpT + k0);
            b1 = *(const float4*)(BpT + k0 + 4);
        } else {
            const float* q = BpN + (size_t)k0 * ldb;
            b0 = *(const float4*)(q);
            b1 = *(const float4*)(q + 4);
        }
        __syncthreads();
        sA[lk+0][lr] = a0.x; sA[lk+1][lr] = a0.y; sA[lk+2][lr] = a0.z; sA[lk+3][lr] = a0.w;
        sA[lk+4][lr] = a1.x; sA[lk+5][lr] = a1.y; sA[lk+6][lr] = a1.z; sA[lk+7][lr] = a1.w;
        if (BT) {
            sB[lk+0][lr] = b0.x; sB[lk+1][lr] = b0.y; sB[lk+2][lr] = b0.z; sB[lk+3][lr] = b0.w;
            sB[lk+4][lr] = b1.x; sB[lk+5][lr] = b1.y; sB[lk+6][lr] = b1.z; sB[lk+7][lr] = b1.w;
        } else {
            sB[bkr][bn8+0] = b0.x; sB[bkr][bn8+1] = b0.y; sB[bkr][bn8+2] = b0.z; sB[bkr][bn8+3] = b0.w;
            sB[bkr][bn8+4] = b1.x; sB[bkr][bn8+5] = b1.y; sB[bkr][bn8+6] = b1.z; sB[bkr][bn8+7] = b1.w;
        }
        __syncthreads();
        #pragma unroll
        for (int kk = 0; kk < 16; kk++) {
            float av[8], bv[8];
            #pragma unroll
            for (int i = 0; i < 4; i++) {
                av[i]   = sA[kk][ty*4 + i];
                av[4+i] = sA[kk][64 + ty*4 + i];
                bv[i]   = sB[kk][tx*4 + i];
                bv[4+i] = sB[kk][64 + tx*4 + i];
            }
            #pragma unroll
            for (int i = 0; i < 8; i++)
                #pragma unroll
                for (int j = 0; j < 8; j++)
                    acc[i][j] = fmaf(av[i], bv[j], acc[i][j]);
        }
    }

    #pragma unroll
    for (int i = 0; i < 8; i++) {
        int r = bm + (i < 4 ? ty*4 + i : 64 + ty*4 + (i-4));
        float* Cr = C + (size_t)r * ldc + bn;
        #pragma unroll
        for (int j = 0; j < 8; j++) {
            int cc = (j < 4 ? tx*4 + j : 64 + tx*4 + (j-4));
            float v = acc[i][j];
            if (bias) v += bias[bn + cc];
            Cr[cc] = v;
        }
    }
}

// ---------------- per-node attention dots (wave per node) -------------------
__global__ __launch_bounds__(256) void node_dots_k(
    const float* __restrict__ h, const float* __restrict__ a_src,
    const float* __restrict__ a_dst, float* __restrict__ as_, float* __restrict__ ad_)
{
    int wid  = (blockIdx.x * 256 + threadIdx.x) >> 6;
    int lane = threadIdx.x & 63;
    if (wid >= NN_) return;
    const float* hr = h + (size_t)wid * HH_;
    float s1 = 0.f, s2 = 0.f;
    #pragma unroll
    for (int j = 0; j < 8; j++) {
        float v = hr[lane + j*64];
        s1 = fmaf(v, a_src[lane + j*64], s1);
        s2 = fmaf(v, a_dst[lane + j*64], s2);
    }
    #pragma unroll
    for (int off = 32; off; off >>= 1) {
        s1 += __shfl_down(s1, off);
        s2 += __shfl_down(s2, off);
    }
    if (lane == 0) { as_[wid] = s1; ad_[wid] = s2; }
}

// ---------------- CSR build ------------------------------------------------
__global__ void count_deg_k(const int* eAB, const int* eBA, int* deg) {
    int i = blockIdx.x * 256 + threadIdx.x;
    if (i >= NE_) return;
    int s, d; edge_sd(i, eAB, eBA, s, d);
    atomicAdd(&deg[d], 1);
}

__global__ __launch_bounds__(256) void scan_k(const int* __restrict__ deg, int* rowstart) {
    __shared__ int part[256];
    int t = threadIdx.x;
    int base = t * 32;
    int loc[32]; int s = 0;
    #pragma unroll
    for (int j = 0; j < 32; j++) { loc[j] = s; s += deg[base + j]; }
    part[t] = s;
    __syncthreads();
    if (t == 0) {
        int a = 0;
        for (int i = 0; i < 256; i++) { int v = part[i]; part[i] = a; a += v; }
        rowstart[NN_] = a;
    }
    __syncthreads();
    int off = part[t];
    #pragma unroll
    for (int j = 0; j < 32; j++) rowstart[base + j] = off + loc[j];
}

__global__ void fill_csr_k(const int* eAB, const int* eBA,
                           const int* __restrict__ rowstart, int* cursor, int* csr) {
    int i = blockIdx.x * 256 + threadIdx.x;
    if (i >= NE_) return;
    int s, d; edge_sd(i, eAB, eBA, s, d);
    int pos = atomicAdd(&cursor[d], 1);
    csr[rowstart[d] + pos] = i;
}

// ---------------- GAT edge passes ------------------------------------------
__global__ void edge_pass1_k(const int* eAB, const int* eBA,
                             const float* __restrict__ as_, const float* __restrict__ ad_,
                             float* evals, unsigned* mkey) {
    int i = blockIdx.x * 256 + threadIdx.x;
    if (i >= NE_) return;
    int s, d; edge_sd(i, eAB, eBA, s, d);
    float e = as_[s] + ad_[d];
    e = (e >= 0.f) ? e : NEG_SLOPE_ * e;
    evals[i] = e;
    atomicMax(&mkey[d], fkey(e));
}

__global__ void edge_pass2_k(const int* eAB, const int* eBA,
                             const unsigned* __restrict__ mkey,
                             float* evals, float* denom) {
    int i = blockIdx.x * 256 + threadIdx.x;
    if (i >= NE_) return;
    int s, d; edge_sd(i, eAB, eBA, s, d);
    float m = finv(mkey[d]);
    float ex = expf(evals[i] - m);
    evals[i] = ex;
    atomicAdd(&denom[d], ex);
}

// ---------------- GAT aggregation (CSR gather, wave per node) ---------------
__global__ __launch_bounds__(256) void gat_agg_k(
    const int* eAB, const int* eBA,
    const int* __restrict__ rowstart, const int* __restrict__ csr,
    const float* __restrict__ evals, const float* __restrict__ denom,
    const float* __restrict__ h, const float* __restrict__ bias,
    float* __restrict__ out, int ldo)
{
    int wid  = (blockIdx.x * 256 + threadIdx.x) >> 6;
    int lane = threadIdx.x & 63;
    if (wid >= NN_) return;
    float acc[8] = {0.f,0.f,0.f,0.f,0.f,0.f,0.f,0.f};
    int beg = rowstart[wid], end = rowstart[wid + 1];
    float rden = 1.0f / denom[wid];
    for (int p = beg; p < end; p++) {
        int eid = csr[p];
        int s, d; edge_sd(eid, eAB, eBA, s, d);
        float alpha = evals[eid] * rden;
        const float* hr = h + (size_t)s * HH_;
        #pragma unroll
        for (int j = 0; j < 8; j++) acc[j] = fmaf(alpha, hr[lane + j*64], acc[j]);
    }
    float* o = out + (size_t)wid * ldo;
    #pragma unroll
    for (int j = 0; j < 8; j++) o[lane + j*64] = acc[j] + bias[lane + j*64];
}

// ---------------- row softmax over 8192 columns ----------------------------
__global__ __launch_bounds__(256) void softmax_k(float* __restrict__ S, float scale) {
    __shared__ float buf[8192];
    __shared__ float red[8];
    int row = blockIdx.x;
    float* r = S + (size_t)row * 8192;
    int t = threadIdx.x;
    float mx = -3.0e38f;
    for (int j = t; j < 8192; j += 256) {
        float v = r[j] * scale;
        buf[j] = v;
        mx = fmaxf(mx, v);
    }
    #pragma unroll
    for (int off = 32; off; off >>= 1) mx = fmaxf(mx, __shfl_down(mx, off));
    if ((t & 63) == 0) red[t >> 6] = mx;
    __syncthreads();
    mx = fmaxf(fmaxf(red[0], red[1]), fmaxf(red[2], red[3]));
    float sum = 0.f;
    for (int j = t; j < 8192; j += 256) {
        float v = expf(buf[j] - mx);
        buf[j] = v;
        sum += v;
    }
    #pragma unroll
    for (int off = 32; off; off >>= 1) sum += __shfl_down(sum, off);
    if ((t & 63) == 0) red[4 + (t >> 6)] = sum;
    __syncthreads();
    float rs = 1.0f / (red[4] + red[5] + red[6] + red[7]);
    for (int j = t; j < 8192; j += 256) r[j] = buf[j] * rs;
}

// ---------------- flush one 512-col half into the FLOAT32 output -----------
// out layout: node-major [8192][1024]; col0 = 0 (local half) or 512 (global)
__global__ __launch_bounds__(256) void store_half_k(
    const float* __restrict__ src, float* __restrict__ out, int col0)
{
    int i = blockIdx.x * 256 + threadIdx.x;      // 0 .. NN_*512-1
    if (i >= NN_ * 512) return;
    int node = i >> 9, c = i & 511;
    out[(size_t)node * 1024 + col0 + c] = src[i];
}

// ===========================================================================
extern "C" void kernel_launch(void* const* d_in, const int* in_sizes, int n_in,
                              void* d_out, int out_size, void* d_ws, size_t ws_size,
                              hipStream_t stream)
{
    const float* x_A    = (const float*)d_in[0];
    const float* x_B    = (const float*)d_in[1];
    const int*   eAB    = (const int*)d_in[2];
    const int*   eBA    = (const int*)d_in[3];
    const float* W_inA  = (const float*)d_in[4];  const float* b_inA  = (const float*)d_in[5];
    const float* W_inB  = (const float*)d_in[6];  const float* b_inB  = (const float*)d_in[7];
    const float* W_in2A = (const float*)d_in[8];  const float* b_in2A = (const float*)d_in[9];
    const float* W_in2B = (const float*)d_in[10]; const float* b_in2B = (const float*)d_in[11];
    const float* Wg1    = (const float*)d_in[12]; const float* a_src1 = (const float*)d_in[13];
    const float* a_dst1 = (const float*)d_in[14]; const float* bg1    = (const float*)d_in[15];
    const float* Wg2    = (const float*)d_in[16]; const float* a_src2 = (const float*)d_in[17];
    const float* a_dst2 = (const float*)d_in[18]; const float* bg2    = (const float*)d_in[19];
    const float* Wqkv   = (const float*)d_in[20]; const float* bqkv   = (const float*)d_in[21];
    const float* Wo     = (const float*)d_in[22]; const float* bo     = (const float*)d_in[23];

    float* out = (float*)d_out;          // reference output dtype is float32

    char* base = (char*)d_ws;
    size_t off = 0;
    auto alloc = [&](size_t nb) -> char* {
        char* p = base + off;
        off = (off + nb + 255) & ~(size_t)255;
        return p;
    };

    float*    bufA  = (float*)alloc((size_t)NN_ * 512 * 4);   // l0 -> l2 (flushed early)
    float*    bufB  = (float*)alloc((size_t)NN_ * 512 * 4);   // h1/h2 -> attnO
    float*    bufC  = (float*)alloc((size_t)NN_ * 512 * 4);   // l1 -> g -> gout
    float*    qkv   = (float*)alloc((size_t)NN_ * 1536 * 4);
    float*    as_   = (float*)alloc(NN_ * 4);
    float*    ad_   = (float*)alloc(NN_ * 4);
    unsigned* mkey  = (unsigned*)alloc(NN_ * 4);
    float*    denom = (float*)alloc(NN_ * 4);
    float*    evals = (float*)alloc((size_t)NE_ * 4);
    int*      deg   = (int*)alloc(NN_ * 4);
    int*      rowst = (int*)alloc((NN_ + 1) * 4);
    int*      cursor= (int*)alloc(NN_ * 4);
    int*      csr   = (int*)alloc((size_t)NE_ * 4);

    // score-chunk buffer: separate if ws allows, else overlay bufA (R=512,
    // safe because local half is flushed to d_out before attention)
    int R; float* Sbuf;
    if (off + (size_t)2048 * 8192 * 4 <= ws_size) { R = 2048; Sbuf = (float*)alloc((size_t)R * 8192 * 4); }
    else if (off + (size_t)1024 * 8192 * 4 <= ws_size) { R = 1024; Sbuf = (float*)alloc((size_t)R * 8192 * 4); }
    else { R = 512; Sbuf = bufA; }

    const int EG = (NE_ + 255) / 256;
    const float scale = 0.044194173824159216f;  // 1/sqrt(512)

    // -------- CSR build -----------------------------------------------------
    hipMemsetAsync(deg, 0, NN_ * 4, stream);
    count_deg_k<<<EG, 256, 0, stream>>>(eAB, eBA, deg);
    scan_k<<<1, 256, 0, stream>>>(deg, rowst);
    hipMemsetAsync(cursor, 0, NN_ * 4, stream);
    fill_csr_k<<<EG, 256, 0, stream>>>(eAB, eBA, rowst, cursor, csr);

    // -------- local branch --------------------------------------------------
    gemm_k<true><<<dim3(4, 32), 256, 0, stream>>>(x_A, W_inA, b_inA, bufA,
                                                  4096, 512, 256, 256, 256, 512);
    gemm_k<true><<<dim3(4, 32), 256, 0, stream>>>(x_B, W_inB, b_inB, bufA + (size_t)4096*512,
                                                  4096, 512, 256, 256, 256, 512);
    // GAT layer 1
    gemm_k<true><<<dim3(4, 64), 256, 0, stream>>>(bufA, Wg1, nullptr, bufB,
                                                  8192, 512, 512, 512, 512, 512);
    node_dots_k<<<NN_/4, 256, 0, stream>>>(bufB, a_src1, a_dst1, as_, ad_);
    hipMemsetAsync(mkey, 0, NN_ * 4, stream);
    hipMemsetAsync(denom, 0, NN_ * 4, stream);
    edge_pass1_k<<<EG, 256, 0, stream>>>(eAB, eBA, as_, ad_, evals, mkey);
    edge_pass2_k<<<EG, 256, 0, stream>>>(eAB, eBA, mkey, evals, denom);
    gat_agg_k<<<NN_/4, 256, 0, stream>>>(eAB, eBA, rowst, csr, evals, denom,
                                         bufB, bg1, bufC, 512);
    // GAT layer 2
    gemm_k<true><<<dim3(4, 64), 256, 0, stream>>>(bufC, Wg2, nullptr, bufB,
                                                  8192, 512, 512, 512, 512, 512);
    node_dots_k<<<NN_/4, 256, 0, stream>>>(bufB, a_src2, a_dst2, as_, ad_);
    hipMemsetAsync(mkey, 0, NN_ * 4, stream);
    hipMemsetAsync(denom, 0, NN_ * 4, stream);
    edge_pass1_k<<<EG, 256, 0, stream>>>(eAB, eBA, as_, ad_, evals, mkey);
    edge_pass2_k<<<EG, 256, 0, stream>>>(eAB, eBA, mkey, evals, denom);
    gat_agg_k<<<NN_/4, 256, 0, stream>>>(eAB, eBA, rowst, csr, evals, denom,
                                         bufB, bg2, bufA, 512);
    // flush local half -> out cols [0,512); frees bufA for Sbuf overlay
    store_half_k<<<(NN_*512)/256, 256, 0, stream>>>(bufA, out, 0);

    // -------- global branch -------------------------------------------------
    gemm_k<true><<<dim3(4, 32), 256, 0, stream>>>(x_A, W_in2A, b_in2A, bufC,
                                                  4096, 512, 256, 256, 256, 512);
    gemm_k<true><<<dim3(4, 32), 256, 0, stream>>>(x_B, W_in2B, b_in2B, bufC + (size_t)4096*512,
                                                  4096, 512, 256, 256, 256, 512);
    gemm_k<true><<<dim3(12, 64), 256, 0, stream>>>(bufC, Wqkv, bqkv, qkv,
                                                   8192, 1536, 512, 512, 512, 1536);
    for (int c0 = 0; c0 < 8192; c0 += R) {
        // S = q_chunk @ k^T
        gemm_k<true><<<dim3(64, R/128), 256, 0, stream>>>(
            qkv + (size_t)c0 * 1536, qkv + 512, nullptr, Sbuf,
            R, 8192, 512, 1536, 1536, 8192);
        softmax_k<<<R, 256, 0, stream>>>(Sbuf, scale);
        // attnO_chunk = P @ v
        gemm_k<false><<<dim3(4, R/128), 256, 0, stream>>>(
            Sbuf, qkv + 1024, nullptr, bufB + (size_t)c0 * 512,
            R, 512, 8192, 8192, 1536, 512);
    }
    gemm_k<true><<<dim3(4, 64), 256, 0, stream>>>(bufB, Wo, bo, bufC,
                                                  8192, 512, 512, 512, 512, 512);
    // flush global half -> out cols [512,1024)
    store_half_k<<<(NN_*512)/256, 256, 0, stream>>>(bufC, out, 512);
}

// Round 7
// 1153.386 us; speedup vs baseline: 6.0676x; 6.0676x over previous
//
#include <hip/hip_runtime.h>
#include <hip/hip_bf16.h>

#define NA_ 4096
#define NB_ 4096
#define NN_ 8192            // total nodes
#define EE_ 131072          // edges per direction
#define NE_ (2*EE_ + NN_)   // homogeneous edges incl. self loops = 270336
#define HH_ 512
#define NEG_SLOPE_ 0.2f

typedef __attribute__((ext_vector_type(4))) float f32x4;
typedef __attribute__((ext_vector_type(8))) short s16x8;

__device__ inline unsigned short f2bf(float v) {
    __hip_bfloat16 h = __float2bfloat16(v);
    return __builtin_bit_cast(unsigned short, h);
}

// ---------------- float-order <-> unsigned-order mapping for atomic max ----
__device__ inline unsigned fkey(float f) {
    unsigned b = __float_as_uint(f);
    return (b & 0x80000000u) ? ~b : (b | 0x80000000u);
}
__device__ inline float finv(unsigned k) {
    return (k & 0x80000000u) ? __uint_as_float(k & 0x7fffffffu)
                             : __uint_as_float(~k);
}

// ---------------- homogeneous edge id -> (src, dst) ------------------------
__device__ inline void edge_sd(int i, const int* __restrict__ eAB,
                               const int* __restrict__ eBA, int& s, int& d) {
    if (i < EE_)            { s = eAB[i];            d = eAB[EE_ + i] + NA_; }
    else if (i < 2 * EE_)   { int j = i - EE_; s = eBA[j] + NA_; d = eBA[EE_ + j]; }
    else                    { s = i - 2 * EE_;       d = s; }
}

// ---------------- f32 -> bf16 cast (vectorized) ----------------------------
__global__ __launch_bounds__(256) void cvtb_k(const float* __restrict__ s,
                                              unsigned short* __restrict__ d, int n4) {
    int i = blockIdx.x * 256 + threadIdx.x;
    if (i >= n4) return;
    float4 v = ((const float4*)s)[i];
    ushort4 o;
    o.x = f2bf(v.x); o.y = f2bf(v.y); o.z = f2bf(v.z); o.w = f2bf(v.w);
    ((ushort4*)d)[i] = o;
}

// ---------------- MFMA bf16 GEMM: C[M,N] = A @ B^T (+bias) -----------------
// A: [M][lda] bf16 row-major; B: [N][ldb] bf16 row-major (B^T layout).
// 256 threads = 4 waves in 2x2 grid; each wave owns (BM/2)x(BN/2) output.
// m97 structure: 128^2 tile, BK=32, global_load_lds width 16, 2 barriers/K-step.
template<int BM, int BN, bool BIAS, typename OutT>
__global__ __launch_bounds__(256) void mgemm_k(
    const unsigned short* __restrict__ A, const unsigned short* __restrict__ B,
    const float* __restrict__ bias, OutT* __restrict__ C,
    int K, int lda, int ldb, int ldc)
{
    constexpr int BK = 32;
    constexpr int WM = BM / 2, WN = BN / 2;
    constexpr int AM = WM / 16, AN = WN / 16;
    constexpr int AISS = BM * 4 / 256, BISS = BN * 4 / 256;
    __shared__ unsigned short sA[BM * BK];
    __shared__ unsigned short sB[BN * BK];
    const int t = threadIdx.x, lane = t & 63, w = t >> 6;
    const int wr = w >> 1, wc = w & 1;
    const int fr = lane & 15, fq = lane >> 4;
    const int bm = blockIdx.y * BM, bn = blockIdx.x * BN;

    f32x4 acc[AM][AN];
    #pragma unroll
    for (int m = 0; m < AM; m++)
        #pragma unroll
        for (int n = 0; n < AN; n++)
            #pragma unroll
            for (int r = 0; r < 4; r++) acc[m][n][r] = 0.f;

    for (int k0 = 0; k0 < K; k0 += BK) {
        __syncthreads();
        #pragma unroll
        for (int i = 0; i < AISS; i++) {
            int slot = i * 256 + t;
            __builtin_amdgcn_global_load_lds(
                (const __attribute__((address_space(1))) unsigned int*)
                    (A + (size_t)(bm + (slot >> 2)) * lda + k0 + (slot & 3) * 8),
                (__attribute__((address_space(3))) unsigned int*)
                    (sA + (i * 256 + w * 64) * 8),
                16, 0, 0);
        }
        #pragma unroll
        for (int i = 0; i < BISS; i++) {
            int slot = i * 256 + t;
            __builtin_amdgcn_global_load_lds(
                (const __attribute__((address_space(1))) unsigned int*)
                    (B + (size_t)(bn + (slot >> 2)) * ldb + k0 + (slot & 3) * 8),
                (__attribute__((address_space(3))) unsigned int*)
                    (sB + (i * 256 + w * 64) * 8),
                16, 0, 0);
        }
        __syncthreads();   // compiler drains vmcnt before s_barrier
        s16x8 a[AM], b[AN];
        #pragma unroll
        for (int m = 0; m < AM; m++)
            a[m] = *(const s16x8*)&sA[(wr * WM + m * 16 + fr) * BK + fq * 8];
        #pragma unroll
        for (int n = 0; n < AN; n++)
            b[n] = *(const s16x8*)&sB[(wc * WN + n * 16 + fr) * BK + fq * 8];
        #pragma unroll
        for (int m = 0; m < AM; m++)
            #pragma unroll
            for (int n = 0; n < AN; n++)
                acc[m][n] = __builtin_amdgcn_mfma_f32_16x16x32_bf16(a[m], b[n], acc[m][n], 0, 0, 0);
    }

    // C/D layout: col = lane&15, row = (lane>>4)*4 + reg  [m89/m91 verified]
    #pragma unroll
    for (int m = 0; m < AM; m++) {
        const int row = bm + wr * WM + m * 16 + fq * 4;
        #pragma unroll
        for (int n = 0; n < AN; n++) {
            const int col = bn + wc * WN + n * 16 + fr;
            const float bv = BIAS ? bias[col] : 0.f;
            #pragma unroll
            for (int r = 0; r < 4; r++) {
                float v = acc[m][n][r] + bv;
                if constexpr (sizeof(OutT) == 2)
                    C[(size_t)(row + r) * ldc + col] = (OutT)f2bf(v);
                else
                    C[(size_t)(row + r) * ldc + col] = v;
            }
        }
    }
}

// ---------------- qkv MFMA GEMM with split epilogue ------------------------
// gb[8192][512] @ Wqkv^T[1536][512] + bqkv -> qb/kb bf16 [8192][512], vT bf16 [512][8192]
__global__ __launch_bounds__(256) void mgemm_qkv_k(
    const unsigned short* __restrict__ A, const unsigned short* __restrict__ B,
    const float* __restrict__ bias,
    unsigned short* __restrict__ qb, unsigned short* __restrict__ kb,
    unsigned short* __restrict__ vT)
{
    constexpr int BM = 128, BN = 128, BK = 32;
    __shared__ unsigned short sA[BM * BK];
    __shared__ unsigned short sB[BN * BK];
    const int t = threadIdx.x, lane = t & 63, w = t >> 6;
    const int wr = w >> 1, wc = w & 1;
    const int fr = lane & 15, fq = lane >> 4;
    const int bm = blockIdx.y * BM, bn = blockIdx.x * BN;

    f32x4 acc[4][4];
    #pragma unroll
    for (int m = 0; m < 4; m++)
        #pragma unroll
        for (int n = 0; n < 4; n++)
            #pragma unroll
            for (int r = 0; r < 4; r++) acc[m][n][r] = 0.f;

    for (int k0 = 0; k0 < 512; k0 += BK) {
        __syncthreads();
        #pragma unroll
        for (int i = 0; i < 2; i++) {
            int slot = i * 256 + t;
            __builtin_amdgcn_global_load_lds(
                (const __attribute__((address_space(1))) unsigned int*)
                    (A + (size_t)(bm + (slot >> 2)) * 512 + k0 + (slot & 3) * 8),
                (__attribute__((address_space(3))) unsigned int*)
                    (sA + (i * 256 + w * 64) * 8), 16, 0, 0);
            __builtin_amdgcn_global_load_lds(
                (const __attribute__((address_space(1))) unsigned int*)
                    (B + (size_t)(bn + (slot >> 2)) * 512 + k0 + (slot & 3) * 8),
                (__attribute__((address_space(3))) unsigned int*)
                    (sB + (i * 256 + w * 64) * 8), 16, 0, 0);
        }
        __syncthreads();
        s16x8 a[4], b[4];
        #pragma unroll
        for (int m = 0; m < 4; m++)
            a[m] = *(const s16x8*)&sA[(wr * 64 + m * 16 + fr) * BK + fq * 8];
        #pragma unroll
        for (int n = 0; n < 4; n++)
            b[n] = *(const s16x8*)&sB[(wc * 64 + n * 16 + fr) * BK + fq * 8];
        #pragma unroll
        for (int m = 0; m < 4; m++)
            #pragma unroll
            for (int n = 0; n < 4; n++)
                acc[m][n] = __builtin_amdgcn_mfma_f32_16x16x32_bf16(a[m], b[n], acc[m][n], 0, 0, 0);
    }

    #pragma unroll
    for (int m = 0; m < 4; m++) {
        const int row = bm + wr * 64 + m * 16 + fq * 4;
        #pragma unroll
        for (int n = 0; n < 4; n++) {
            const int col = bn + wc * 64 + n * 16 + fr;
            const float bv = bias[col];
            #pragma unroll
            for (int r = 0; r < 4; r++) {
                float v = acc[m][n][r] + bv;
                unsigned short u = f2bf(v);
                if (col < 512)       qb[(size_t)(row + r) * 512 + col] = u;
                else if (col < 1024) kb[(size_t)(row + r) * 512 + (col - 512)] = u;
                else                 vT[(size_t)(col - 1024) * 8192 + (row + r)] = u;
            }
        }
    }
}

// ---------------- f32 GEMM (kept for Wg1/Wg2): C = A @ B^T ------------------
__global__ __launch_bounds__(256) void gemm_k(
    const float* __restrict__ A, const float* __restrict__ B,
    const float* __restrict__ bias, float* __restrict__ C,
    int M, int N, int K, int lda, int ldb, int ldc)
{
    __shared__ float sA[16][129];
    __shared__ float sB[16][129];
    const int t  = threadIdx.x;
    const int tx = t & 15, ty = t >> 4;
    const int bm = blockIdx.y * 128, bn = blockIdx.x * 128;

    float acc[8][8] = {{0.f}};
    const int lr = t >> 1;
    const int lk = (t & 1) * 8;
    const float* Ap = A + (size_t)(bm + lr) * lda + lk;
    const float* BpT = B + (size_t)(bn + lr) * ldb + lk;

    for (int k0 = 0; k0 < K; k0 += 16) {
        float4 a0 = *(const float4*)(Ap + k0);
        float4 a1 = *(const float4*)(Ap + k0 + 4);
        float4 b0 = *(const float4*)(BpT + k0);
        float4 b1 = *(const float4*)(BpT + k0 + 4);
        __syncthreads();
        sA[lk+0][lr] = a0.x; sA[lk+1][lr] = a0.y; sA[lk+2][lr] = a0.z; sA[lk+3][lr] = a0.w;
        sA[lk+4][lr] = a1.x; sA[lk+5][lr] = a1.y; sA[lk+6][lr] = a1.z; sA[lk+7][lr] = a1.w;
        sB[lk+0][lr] = b0.x; sB[lk+1][lr] = b0.y; sB[lk+2][lr] = b0.z; sB[lk+3][lr] = b0.w;
        sB[lk+4][lr] = b1.x; sB[lk+5][lr] = b1.y; sB[lk+6][lr] = b1.z; sB[lk+7][lr] = b1.w;
        __syncthreads();
        #pragma unroll
        for (int kk = 0; kk < 16; kk++) {
            float av[8], bv[8];
            #pragma unroll
            for (int i = 0; i < 4; i++) {
                av[i]   = sA[kk][ty*4 + i];
                av[4+i] = sA[kk][64 + ty*4 + i];
                bv[i]   = sB[kk][tx*4 + i];
                bv[4+i] = sB[kk][64 + tx*4 + i];
            }
            #pragma unroll
            for (int i = 0; i < 8; i++)
                #pragma unroll
                for (int j = 0; j < 8; j++)
                    acc[i][j] = fmaf(av[i], bv[j], acc[i][j]);
        }
    }

    #pragma unroll
    for (int i = 0; i < 8; i++) {
        int r = bm + (i < 4 ? ty*4 + i : 64 + ty*4 + (i-4));
        float* Cr = C + (size_t)r * ldc + bn;
        #pragma unroll
        for (int j = 0; j < 8; j++) {
            int cc = (j < 4 ? tx*4 + j : 64 + tx*4 + (j-4));
            float v = acc[i][j];
            if (bias) v += bias[bn + cc];
            Cr[cc] = v;
        }
    }
}

// ---------------- per-node attention dots (wave per node) -------------------
__global__ __launch_bounds__(256) void node_dots_k(
    const float* __restrict__ h, const float* __restrict__ a_src,
    const float* __restrict__ a_dst, float* __restrict__ as_, float* __restrict__ ad_)
{
    int wid  = (blockIdx.x * 256 + threadIdx.x) >> 6;
    int lane = threadIdx.x & 63;
    if (wid >= NN_) return;
    const float* hr = h + (size_t)wid * HH_;
    float s1 = 0.f, s2 = 0.f;
    #pragma unroll
    for (int j = 0; j < 8; j++) {
        float v = hr[lane + j*64];
        s1 = fmaf(v, a_src[lane + j*64], s1);
        s2 = fmaf(v, a_dst[lane + j*64], s2);
    }
    #pragma unroll
    for (int off = 32; off; off >>= 1) {
        s1 += __shfl_down(s1, off);
        s2 += __shfl_down(s2, off);
    }
    if (lane == 0) { as_[wid] = s1; ad_[wid] = s2; }
}

// ---------------- CSR build ------------------------------------------------
__global__ void count_deg_k(const int* eAB, const int* eBA, int* deg) {
    int i = blockIdx.x * 256 + threadIdx.x;
    if (i >= NE_) return;
    int s, d; edge_sd(i, eAB, eBA, s, d);
    atomicAdd(&deg[d], 1);
}

__global__ __launch_bounds__(256) void scan_k(const int* __restrict__ deg, int* rowstart) {
    __shared__ int part[256];
    int t = threadIdx.x;
    int base = t * 32;
    int loc[32]; int s = 0;
    #pragma unroll
    for (int j = 0; j < 32; j++) { loc[j] = s; s += deg[base + j]; }
    part[t] = s;
    __syncthreads();
    if (t == 0) {
        int a = 0;
        for (int i = 0; i < 256; i++) { int v = part[i]; part[i] = a; a += v; }
        rowstart[NN_] = a;
    }
    __syncthreads();
    int off = part[t];
    #pragma unroll
    for (int j = 0; j < 32; j++) rowstart[base + j] = off + loc[j];
}

__global__ void fill_csr_k(const int* eAB, const int* eBA,
                           const int* __restrict__ rowstart, int* cursor, int* csr) {
    int i = blockIdx.x * 256 + threadIdx.x;
    if (i >= NE_) return;
    int s, d; edge_sd(i, eAB, eBA, s, d);
    int pos = atomicAdd(&cursor[d], 1);
    csr[rowstart[d] + pos] = i;
}

// ---------------- GAT edge passes ------------------------------------------
__global__ void edge_pass1_k(const int* eAB, const int* eBA,
                             const float* __restrict__ as_, const float* __restrict__ ad_,
                             float* evals, unsigned* mkey) {
    int i = blockIdx.x * 256 + threadIdx.x;
    if (i >= NE_) return;
    int s, d; edge_sd(i, eAB, eBA, s, d);
    float e = as_[s] + ad_[d];
    e = (e >= 0.f) ? e : NEG_SLOPE_ * e;
    evals[i] = e;
    atomicMax(&mkey[d], fkey(e));
}

__global__ void edge_pass2_k(const int* eAB, const int* eBA,
                             const unsigned* __restrict__ mkey,
                             float* evals, float* denom) {
    int i = blockIdx.x * 256 + threadIdx.x;
    if (i >= NE_) return;
    int s, d; edge_sd(i, eAB, eBA, s, d);
    float m = finv(mkey[d]);
    float ex = expf(evals[i] - m);
    evals[i] = ex;
    atomicAdd(&denom[d], ex);
}

// ---------------- GAT aggregation (CSR gather, wave per node) ---------------
__global__ __launch_bounds__(256) void gat_agg_k(
    const int* eAB, const int* eBA,
    const int* __restrict__ rowstart, const int* __restrict__ csr,
    const float* __restrict__ evals, const float* __restrict__ denom,
    const float* __restrict__ h, const float* __restrict__ bias,
    float* __restrict__ out, int ldo)
{
    int wid  = (blockIdx.x * 256 + threadIdx.x) >> 6;
    int lane = threadIdx.x & 63;
    if (wid >= NN_) return;
    float acc[8] = {0.f,0.f,0.f,0.f,0.f,0.f,0.f,0.f};
    int beg = rowstart[wid], end = rowstart[wid + 1];
    float rden = 1.0f / denom[wid];
    for (int p = beg; p < end; p++) {
        int eid = csr[p];
        int s, d; edge_sd(eid, eAB, eBA, s, d);
        float alpha = evals[eid] * rden;
        const float* hr = h + (size_t)s * HH_;
        #pragma unroll
        for (int j = 0; j < 8; j++) acc[j] = fmaf(alpha, hr[lane + j*64], acc[j]);
    }
    float* o = out + (size_t)wid * ldo;
    #pragma unroll
    for (int j = 0; j < 8; j++) o[lane + j*64] = acc[j] + bias[lane + j*64];
}

// ---------------- bf16 row softmax over 8192 columns (in place) ------------
__global__ __launch_bounds__(256) void softmax_bf16_k(unsigned short* __restrict__ S,
                                                      float scale) {
    __shared__ float red[8];
    const int row = blockIdx.x, t = threadIdx.x;
    uint4* rp = (uint4*)(S + (size_t)row * 8192);
    float v[32];
    uint4 u[4];
    float mx = -3.0e38f;
    #pragma unroll
    for (int i = 0; i < 4; i++) {
        u[i] = rp[t + i * 256];
        const unsigned* uw = (const unsigned*)&u[i];
        #pragma unroll
        for (int j = 0; j < 4; j++) {
            float lo = __uint_as_float(uw[j] << 16) * scale;
            float hi = __uint_as_float(uw[j] & 0xffff0000u) * scale;
            v[i*8 + 2*j]     = lo;
            v[i*8 + 2*j + 1] = hi;
            mx = fmaxf(mx, fmaxf(lo, hi));
        }
    }
    #pragma unroll
    for (int o = 32; o; o >>= 1) mx = fmaxf(mx, __shfl_down(mx, o));
    if ((t & 63) == 0) red[t >> 6] = mx;
    __syncthreads();
    mx = fmaxf(fmaxf(red[0], red[1]), fmaxf(red[2], red[3]));
    float sum = 0.f;
    #pragma unroll
    for (int i = 0; i < 32; i++) { float p = expf(v[i] - mx); v[i] = p; sum += p; }
    #pragma unroll
    for (int o = 32; o; o >>= 1) sum += __shfl_down(sum, o);
    if ((t & 63) == 0) red[4 + (t >> 6)] = sum;
    __syncthreads();
    const float rs = 1.0f / (red[4] + red[5] + red[6] + red[7]);
    #pragma unroll
    for (int i = 0; i < 4; i++) {
        unsigned* uw = (unsigned*)&u[i];
        #pragma unroll
        for (int j = 0; j < 4; j++)
            uw[j] = (unsigned)f2bf(v[i*8 + 2*j] * rs)
                  | ((unsigned)f2bf(v[i*8 + 2*j + 1] * rs) << 16);
        rp[t + i * 256] = u[i];
    }
}

// ---------------- flush one 512-col half into the f32 output ----------------
__global__ __launch_bounds__(256) void store_half_k(
    const float* __restrict__ src, float* __restrict__ out, int col0)
{
    int i = blockIdx.x * 256 + threadIdx.x;
    if (i >= NN_ * 512) return;
    int node = i >> 9, c = i & 511;
    out[(size_t)node * 1024 + col0 + c] = src[i];
}

// ===========================================================================
extern "C" void kernel_launch(void* const* d_in, const int* in_sizes, int n_in,
                              void* d_out, int out_size, void* d_ws, size_t ws_size,
                              hipStream_t stream)
{
    const float* x_A    = (const float*)d_in[0];
    const float* x_B    = (const float*)d_in[1];
    const int*   eAB    = (const int*)d_in[2];
    const int*   eBA    = (const int*)d_in[3];
    const float* W_inA  = (const float*)d_in[4];  const float* b_inA  = (const float*)d_in[5];
    const float* W_inB  = (const float*)d_in[6];  const float* b_inB  = (const float*)d_in[7];
    const float* W_in2A = (const float*)d_in[8];  const float* b_in2A = (const float*)d_in[9];
    const float* W_in2B = (const float*)d_in[10]; const float* b_in2B = (const float*)d_in[11];
    const float* Wg1    = (const float*)d_in[12]; const float* a_src1 = (const float*)d_in[13];
    const float* a_dst1 = (const float*)d_in[14]; const float* bg1    = (const float*)d_in[15];
    const float* Wg2    = (const float*)d_in[16]; const float* a_src2 = (const float*)d_in[17];
    const float* a_dst2 = (const float*)d_in[18]; const float* bg2    = (const float*)d_in[19];
    const float* Wqkv   = (const float*)d_in[20]; const float* bqkv   = (const float*)d_in[21];
    const float* Wo     = (const float*)d_in[22]; const float* bo     = (const float*)d_in[23];

    float* out = (float*)d_out;

    char* base = (char*)d_ws;
    size_t off = 0;
    auto alloc = [&](size_t nb) -> char* {
        char* p = base + off;
        off = (off + nb + 255) & ~(size_t)255;
        return p;
    };

    float*          bufA  = (float*)alloc((size_t)NN_ * 512 * 4);
    float*          bufB  = (float*)alloc((size_t)NN_ * 512 * 4);
    float*          bufC  = (float*)alloc((size_t)NN_ * 512 * 4);
    float*          as_   = (float*)alloc(NN_ * 4);
    float*          ad_   = (float*)alloc(NN_ * 4);
    unsigned*       mkey  = (unsigned*)alloc(NN_ * 4);
    float*          denom = (float*)alloc(NN_ * 4);
    float*          evals = (float*)alloc((size_t)NE_ * 4);
    int*            deg   = (int*)alloc(NN_ * 4);
    int*            rowst = (int*)alloc((NN_ + 1) * 4);
    int*            cursor= (int*)alloc(NN_ * 4);
    int*            csr   = (int*)alloc((size_t)NE_ * 4);
    unsigned short* xbA   = (unsigned short*)alloc((size_t)NA_ * 256 * 2);
    unsigned short* xbB   = (unsigned short*)alloc((size_t)NB_ * 256 * 2);
    unsigned short* WbinA = (unsigned short*)alloc((size_t)512 * 256 * 2);
    unsigned short* WbinB = (unsigned short*)alloc((size_t)512 * 256 * 2);
    unsigned short* Wbin2A= (unsigned short*)alloc((size_t)512 * 256 * 2);
    unsigned short* Wbin2B= (unsigned short*)alloc((size_t)512 * 256 * 2);
    unsigned short* Wbqkv = (unsigned short*)alloc((size_t)1536 * 512 * 2);
    unsigned short* Wbo   = (unsigned short*)alloc((size_t)512 * 512 * 2);
    unsigned short* qb    = (unsigned short*)alloc((size_t)NN_ * 512 * 2);
    unsigned short* kb    = (unsigned short*)alloc((size_t)NN_ * 512 * 2);
    unsigned short* vT    = (unsigned short*)alloc((size_t)512 * NN_ * 2);

    // score-chunk buffer (bf16): largest R that fits
    int R;
    if (off + (size_t)2048 * 8192 * 2 <= ws_size)      R = 2048;
    else if (off + (size_t)1024 * 8192 * 2 <= ws_size) R = 1024;
    else                                               R = 512;
    unsigned short* Sb = (unsigned short*)alloc((size_t)R * 8192 * 2);

    // gb/ab bf16 overlays inside bufA (bufA is free after the local flush)
    unsigned short* gb = (unsigned short*)bufA;
    unsigned short* ab = (unsigned short*)bufA + (size_t)NN_ * 512;

    const int EG = (NE_ + 255) / 256;
    const float scale = 0.044194173824159216f;  // 1/sqrt(512)

    // -------- weight / input casts to bf16 ---------------------------------
    auto cvtb = [&](const float* s, unsigned short* d, int n) {
        cvtb_k<<<(n/4 + 255) / 256, 256, 0, stream>>>(s, d, n / 4);
    };
    cvtb(x_A,    xbA,    NA_ * 256);
    cvtb(x_B,    xbB,    NB_ * 256);
    cvtb(W_inA,  WbinA,  512 * 256);
    cvtb(W_inB,  WbinB,  512 * 256);
    cvtb(W_in2A, Wbin2A, 512 * 256);
    cvtb(W_in2B, Wbin2B, 512 * 256);
    cvtb(Wqkv,   Wbqkv,  1536 * 512);
    cvtb(Wo,     Wbo,    512 * 512);

    // -------- CSR build -----------------------------------------------------
    hipMemsetAsync(deg, 0, NN_ * 4, stream);
    count_deg_k<<<EG, 256, 0, stream>>>(eAB, eBA, deg);
    scan_k<<<1, 256, 0, stream>>>(deg, rowst);
    hipMemsetAsync(cursor, 0, NN_ * 4, stream);
    fill_csr_k<<<EG, 256, 0, stream>>>(eAB, eBA, rowst, cursor, csr);

    // -------- local branch --------------------------------------------------
    mgemm_k<128,128,true,float><<<dim3(4, 32), 256, 0, stream>>>(
        xbA, WbinA, b_inA, bufA, 256, 256, 256, 512);
    mgemm_k<128,128,true,float><<<dim3(4, 32), 256, 0, stream>>>(
        xbB, WbinB, b_inB, bufA + (size_t)4096*512, 256, 256, 256, 512);
    // GAT layer 1 (f32 GEMM retained for precision)
    gemm_k<<<dim3(4, 64), 256, 0, stream>>>(bufA, Wg1, nullptr, bufB,
                                            8192, 512, 512, 512, 512, 512);
    node_dots_k<<<NN_/4, 256, 0, stream>>>(bufB, a_src1, a_dst1, as_, ad_);
    hipMemsetAsync(mkey, 0, NN_ * 4, stream);
    hipMemsetAsync(denom, 0, NN_ * 4, stream);
    edge_pass1_k<<<EG, 256, 0, stream>>>(eAB, eBA, as_, ad_, evals, mkey);
    edge_pass2_k<<<EG, 256, 0, stream>>>(eAB, eBA, mkey, evals, denom);
    gat_agg_k<<<NN_/4, 256, 0, stream>>>(eAB, eBA, rowst, csr, evals, denom,
                                         bufB, bg1, bufC, 512);
    // GAT layer 2
    gemm_k<<<dim3(4, 64), 256, 0, stream>>>(bufC, Wg2, nullptr, bufB,
                                            8192, 512, 512, 512, 512, 512);
    node_dots_k<<<NN_/4, 256, 0, stream>>>(bufB, a_src2, a_dst2, as_, ad_);
    hipMemsetAsync(mkey, 0, NN_ * 4, stream);
    hipMemsetAsync(denom, 0, NN_ * 4, stream);
    edge_pass1_k<<<EG, 256, 0, stream>>>(eAB, eBA, as_, ad_, evals, mkey);
    edge_pass2_k<<<EG, 256, 0, stream>>>(eAB, eBA, mkey, evals, denom);
    gat_agg_k<<<NN_/4, 256, 0, stream>>>(eAB, eBA, rowst, csr, evals, denom,
                                         bufB, bg2, bufA, 512);
    store_half_k<<<(NN_*512)/256, 256, 0, stream>>>(bufA, out, 0);  // frees bufA

    // -------- global branch -------------------------------------------------
    mgemm_k<128,128,true,float><<<dim3(4, 32), 256, 0, stream>>>(
        xbA, Wbin2A, b_in2A, bufC, 256, 256, 256, 512);
    mgemm_k<128,128,true,float><<<dim3(4, 32), 256, 0, stream>>>(
        xbB, Wbin2B, b_in2B, bufC + (size_t)4096*512, 256, 256, 256, 512);
    cvtb(bufC, gb, NN_ * 512);                      // g -> bf16 (in bufA)
    mgemm_qkv_k<<<dim3(12, 64), 256, 0, stream>>>(gb, Wbqkv, bqkv, qb, kb, vT);
    for (int c0 = 0; c0 < 8192; c0 += R) {
        mgemm_k<128,128,false,unsigned short><<<dim3(64, R/128), 256, 0, stream>>>(
            qb + (size_t)c0 * 512, kb, nullptr, Sb, 512, 512, 512, 8192);
        softmax_bf16_k<<<R, 256, 0, stream>>>(Sb, scale);
        mgemm_k<64,64,false,float><<<dim3(8, R/64), 256, 0, stream>>>(
            Sb, vT, nullptr, bufB + (size_t)c0 * 512, 8192, 8192, 8192, 512);
    }
    cvtb(bufB, ab, NN_ * 512);                      // attnO -> bf16 (in bufA)
    mgemm_k<128,128,true,float><<<dim3(4, 64), 256, 0, stream>>>(
        ab, Wbo, bo, bufC, 512, 512, 512, 512);
    store_half_k<<<(NN_*512)/256, 256, 0, stream>>>(bufC, out, 512);
}

// Round 8
// 856.305 us; speedup vs baseline: 8.1726x; 1.3469x over previous
//
#include <hip/hip_runtime.h>
#include <hip/hip_bf16.h>

#define NA_ 4096
#define NB_ 4096
#define NN_ 8192            // total nodes
#define EE_ 131072          // edges per direction
#define NE_ (2*EE_ + NN_)   // homogeneous edges incl. self loops = 270336
#define HH_ 512
#define NEG_SLOPE_ 0.2f

typedef __attribute__((ext_vector_type(4))) float f32x4;
typedef __attribute__((ext_vector_type(8))) short s16x8;

__device__ inline unsigned short f2bf(float v) {
    __hip_bfloat16 h = __float2bfloat16(v);
    return __builtin_bit_cast(unsigned short, h);
}
__device__ inline float bf2f(unsigned short u) {
    return __uint_as_float(((unsigned)u) << 16);
}

// ---------------- float-order <-> unsigned-order mapping for atomic max ----
__device__ inline unsigned fkey(float f) {
    unsigned b = __float_as_uint(f);
    return (b & 0x80000000u) ? ~b : (b | 0x80000000u);
}
__device__ inline float finv(unsigned k) {
    return (k & 0x80000000u) ? __uint_as_float(k & 0x7fffffffu)
                             : __uint_as_float(~k);
}

// ---------------- homogeneous edge id -> (src, dst) ------------------------
__device__ inline void edge_sd(int i, const int* __restrict__ eAB,
                               const int* __restrict__ eBA, int& s, int& d) {
    if (i < EE_)            { s = eAB[i];            d = eAB[EE_ + i] + NA_; }
    else if (i < 2 * EE_)   { int j = i - EE_; s = eBA[j] + NA_; d = eBA[EE_ + j]; }
    else                    { s = i - 2 * EE_;       d = s; }
}

// ---------------- f32 -> bf16 cast (vectorized) ----------------------------
__global__ __launch_bounds__(256) void cvtb_k(const float* __restrict__ s,
                                              unsigned short* __restrict__ d, int n4) {
    int i = blockIdx.x * 256 + threadIdx.x;
    if (i >= n4) return;
    float4 v = ((const float4*)s)[i];
    ushort4 o;
    o.x = f2bf(v.x); o.y = f2bf(v.y); o.z = f2bf(v.z); o.w = f2bf(v.w);
    ((ushort4*)d)[i] = o;
}

// ---------------- f32 -> (bf16 hi, bf16 lo) split cast ---------------------
__global__ __launch_bounds__(256) void csplit_k(const float* __restrict__ s,
                                                unsigned short* __restrict__ hi,
                                                unsigned short* __restrict__ lo, int n4) {
    int i = blockIdx.x * 256 + threadIdx.x;
    if (i >= n4) return;
    float4 v = ((const float4*)s)[i];
    ushort4 h, l;
    h.x = f2bf(v.x); l.x = f2bf(v.x - bf2f(h.x));
    h.y = f2bf(v.y); l.y = f2bf(v.y - bf2f(h.y));
    h.z = f2bf(v.z); l.z = f2bf(v.z - bf2f(h.z));
    h.w = f2bf(v.w); l.w = f2bf(v.w - bf2f(h.w));
    ((ushort4*)hi)[i] = h;
    ((ushort4*)lo)[i] = l;
}

// ---------------- MFMA bf16 GEMM: C[M,N] = A @ B^T (+bias) -----------------
template<int BM, int BN, bool BIAS, typename OutT>
__global__ __launch_bounds__(256) void mgemm_k(
    const unsigned short* __restrict__ A, const unsigned short* __restrict__ B,
    const float* __restrict__ bias, OutT* __restrict__ C,
    int K, int lda, int ldb, int ldc)
{
    constexpr int BK = 32;
    constexpr int WM = BM / 2, WN = BN / 2;
    constexpr int AM = WM / 16, AN = WN / 16;
    constexpr int AISS = BM * 4 / 256, BISS = BN * 4 / 256;
    __shared__ unsigned short sA[BM * BK];
    __shared__ unsigned short sB[BN * BK];
    const int t = threadIdx.x, lane = t & 63, w = t >> 6;
    const int wr = w >> 1, wc = w & 1;
    const int fr = lane & 15, fq = lane >> 4;
    const int bm = blockIdx.y * BM, bn = blockIdx.x * BN;

    f32x4 acc[AM][AN];
    #pragma unroll
    for (int m = 0; m < AM; m++)
        #pragma unroll
        for (int n = 0; n < AN; n++)
            #pragma unroll
            for (int r = 0; r < 4; r++) acc[m][n][r] = 0.f;

    for (int k0 = 0; k0 < K; k0 += BK) {
        __syncthreads();
        #pragma unroll
        for (int i = 0; i < AISS; i++) {
            int slot = i * 256 + t;
            __builtin_amdgcn_global_load_lds(
                (const __attribute__((address_space(1))) unsigned int*)
                    (A + (size_t)(bm + (slot >> 2)) * lda + k0 + (slot & 3) * 8),
                (__attribute__((address_space(3))) unsigned int*)
                    (sA + (i * 256 + w * 64) * 8), 16, 0, 0);
        }
        #pragma unroll
        for (int i = 0; i < BISS; i++) {
            int slot = i * 256 + t;
            __builtin_amdgcn_global_load_lds(
                (const __attribute__((address_space(1))) unsigned int*)
                    (B + (size_t)(bn + (slot >> 2)) * ldb + k0 + (slot & 3) * 8),
                (__attribute__((address_space(3))) unsigned int*)
                    (sB + (i * 256 + w * 64) * 8), 16, 0, 0);
        }
        __syncthreads();
        s16x8 a[AM], b[AN];
        #pragma unroll
        for (int m = 0; m < AM; m++)
            a[m] = *(const s16x8*)&sA[(wr * WM + m * 16 + fr) * BK + fq * 8];
        #pragma unroll
        for (int n = 0; n < AN; n++)
            b[n] = *(const s16x8*)&sB[(wc * WN + n * 16 + fr) * BK + fq * 8];
        #pragma unroll
        for (int m = 0; m < AM; m++)
            #pragma unroll
            for (int n = 0; n < AN; n++)
                acc[m][n] = __builtin_amdgcn_mfma_f32_16x16x32_bf16(a[m], b[n], acc[m][n], 0, 0, 0);
    }

    // C/D layout: col = lane&15, row = (lane>>4)*4 + reg
    #pragma unroll
    for (int m = 0; m < AM; m++) {
        const int row = bm + wr * WM + m * 16 + fq * 4;
        #pragma unroll
        for (int n = 0; n < AN; n++) {
            const int col = bn + wc * WN + n * 16 + fr;
            const float bv = BIAS ? bias[col] : 0.f;
            #pragma unroll
            for (int r = 0; r < 4; r++) {
                float v = acc[m][n][r] + bv;
                if constexpr (sizeof(OutT) == 2)
                    C[(size_t)(row + r) * ldc + col] = (OutT)f2bf(v);
                else
                    C[(size_t)(row + r) * ldc + col] = v;
            }
        }
    }
}

// ---------------- split-precision MFMA GEMM (~f32 accuracy) ----------------
// C = (Ahi+Alo) @ (Bhi+Blo)^T dropping lo*lo: 3 MFMA per fragment pair.
__global__ __launch_bounds__(256) void mgemm3_k(
    const unsigned short* __restrict__ Ahi, const unsigned short* __restrict__ Alo,
    const unsigned short* __restrict__ Bhi, const unsigned short* __restrict__ Blo,
    float* __restrict__ C, int K, int lda, int ldb, int ldc)
{
    constexpr int BM = 128, BN = 128, BK = 32;
    __shared__ unsigned short sAh[BM * BK], sAl[BM * BK];
    __shared__ unsigned short sBh[BN * BK], sBl[BN * BK];
    const int t = threadIdx.x, lane = t & 63, w = t >> 6;
    const int wr = w >> 1, wc = w & 1;
    const int fr = lane & 15, fq = lane >> 4;
    const int bm = blockIdx.y * BM, bn = blockIdx.x * BN;

    f32x4 acc[4][4];
    #pragma unroll
    for (int m = 0; m < 4; m++)
        #pragma unroll
        for (int n = 0; n < 4; n++)
            #pragma unroll
            for (int r = 0; r < 4; r++) acc[m][n][r] = 0.f;

    for (int k0 = 0; k0 < K; k0 += BK) {
        __syncthreads();
        #pragma unroll
        for (int i = 0; i < 2; i++) {
            int slot = i * 256 + t;
            size_t ga = (size_t)(bm + (slot >> 2)) * lda + k0 + (slot & 3) * 8;
            size_t gb = (size_t)(bn + (slot >> 2)) * ldb + k0 + (slot & 3) * 8;
            unsigned loff = (unsigned)(i * 256 + w * 64) * 8;
            __builtin_amdgcn_global_load_lds(
                (const __attribute__((address_space(1))) unsigned int*)(Ahi + ga),
                (__attribute__((address_space(3))) unsigned int*)(sAh + loff), 16, 0, 0);
            __builtin_amdgcn_global_load_lds(
                (const __attribute__((address_space(1))) unsigned int*)(Alo + ga),
                (__attribute__((address_space(3))) unsigned int*)(sAl + loff), 16, 0, 0);
            __builtin_amdgcn_global_load_lds(
                (const __attribute__((address_space(1))) unsigned int*)(Bhi + gb),
                (__attribute__((address_space(3))) unsigned int*)(sBh + loff), 16, 0, 0);
            __builtin_amdgcn_global_load_lds(
                (const __attribute__((address_space(1))) unsigned int*)(Blo + gb),
                (__attribute__((address_space(3))) unsigned int*)(sBl + loff), 16, 0, 0);
        }
        __syncthreads();
        s16x8 ah[4], al[4], bh[4], bl[4];
        #pragma unroll
        for (int m = 0; m < 4; m++) {
            int o = (wr * 64 + m * 16 + fr) * BK + fq * 8;
            ah[m] = *(const s16x8*)&sAh[o];
            al[m] = *(const s16x8*)&sAl[o];
        }
        #pragma unroll
        for (int n = 0; n < 4; n++) {
            int o = (wc * 64 + n * 16 + fr) * BK + fq * 8;
            bh[n] = *(const s16x8*)&sBh[o];
            bl[n] = *(const s16x8*)&sBl[o];
        }
        #pragma unroll
        for (int m = 0; m < 4; m++)
            #pragma unroll
            for (int n = 0; n < 4; n++) {
                acc[m][n] = __builtin_amdgcn_mfma_f32_16x16x32_bf16(ah[m], bh[n], acc[m][n], 0, 0, 0);
                acc[m][n] = __builtin_amdgcn_mfma_f32_16x16x32_bf16(ah[m], bl[n], acc[m][n], 0, 0, 0);
                acc[m][n] = __builtin_amdgcn_mfma_f32_16x16x32_bf16(al[m], bh[n], acc[m][n], 0, 0, 0);
            }
    }

    #pragma unroll
    for (int m = 0; m < 4; m++) {
        const int row = bm + wr * 64 + m * 16 + fq * 4;
        #pragma unroll
        for (int n = 0; n < 4; n++) {
            const int col = bn + wc * 64 + n * 16 + fr;
            #pragma unroll
            for (int r = 0; r < 4; r++)
                C[(size_t)(row + r) * ldc + col] = acc[m][n][r];
        }
    }
}

// ---------------- PV split-K MFMA GEMM -------------------------------------
// partial[z][i][f] = sum_{j in seg z} P[i][j] * vT[f][j]
__global__ __launch_bounds__(256) void mgemm_pv_k(
    const unsigned short* __restrict__ A, const unsigned short* __restrict__ B,
    float* __restrict__ C, int kseg, size_t segstride)
{
    constexpr int BM = 128, BN = 128, BK = 32;
    __shared__ unsigned short sA[BM * BK];
    __shared__ unsigned short sB[BN * BK];
    const int t = threadIdx.x, lane = t & 63, w = t >> 6;
    const int wr = w >> 1, wc = w & 1;
    const int fr = lane & 15, fq = lane >> 4;
    const int bm = blockIdx.y * BM, bn = blockIdx.x * BN;
    const int kofs = blockIdx.z * kseg;

    f32x4 acc[4][4];
    #pragma unroll
    for (int m = 0; m < 4; m++)
        #pragma unroll
        for (int n = 0; n < 4; n++)
            #pragma unroll
            for (int r = 0; r < 4; r++) acc[m][n][r] = 0.f;

    for (int k0 = 0; k0 < kseg; k0 += BK) {
        __syncthreads();
        #pragma unroll
        for (int i = 0; i < 2; i++) {
            int slot = i * 256 + t;
            __builtin_amdgcn_global_load_lds(
                (const __attribute__((address_space(1))) unsigned int*)
                    (A + (size_t)(bm + (slot >> 2)) * 8192 + kofs + k0 + (slot & 3) * 8),
                (__attribute__((address_space(3))) unsigned int*)
                    (sA + (i * 256 + w * 64) * 8), 16, 0, 0);
            __builtin_amdgcn_global_load_lds(
                (const __attribute__((address_space(1))) unsigned int*)
                    (B + (size_t)(bn + (slot >> 2)) * 8192 + kofs + k0 + (slot & 3) * 8),
                (__attribute__((address_space(3))) unsigned int*)
                    (sB + (i * 256 + w * 64) * 8), 16, 0, 0);
        }
        __syncthreads();
        s16x8 a[4], b[4];
        #pragma unroll
        for (int m = 0; m < 4; m++)
            a[m] = *(const s16x8*)&sA[(wr * 64 + m * 16 + fr) * BK + fq * 8];
        #pragma unroll
        for (int n = 0; n < 4; n++)
            b[n] = *(const s16x8*)&sB[(wc * 64 + n * 16 + fr) * BK + fq * 8];
        #pragma unroll
        for (int m = 0; m < 4; m++)
            #pragma unroll
            for (int n = 0; n < 4; n++)
                acc[m][n] = __builtin_amdgcn_mfma_f32_16x16x32_bf16(a[m], b[n], acc[m][n], 0, 0, 0);
    }

    float* Cz = C + (size_t)blockIdx.z * segstride;
    #pragma unroll
    for (int m = 0; m < 4; m++) {
        const int row = bm + wr * 64 + m * 16 + fq * 4;
        #pragma unroll
        for (int n = 0; n < 4; n++) {
            const int col = bn + wc * 64 + n * 16 + fr;
            #pragma unroll
            for (int r = 0; r < 4; r++)
                Cz[(size_t)(row + r) * 512 + col] = acc[m][n][r];
        }
    }
}

// ---------------- reduce split-K partials ----------------------------------
__global__ __launch_bounds__(256) void radd_k(const float* __restrict__ src,
                                              float* __restrict__ dst,
                                              int n4, int segs, size_t stride4) {
    int i = blockIdx.x * 256 + threadIdx.x;
    if (i >= n4) return;
    float4 a = ((const float4*)src)[i];
    for (int s = 1; s < segs; s++) {
        float4 b = ((const float4*)src)[i + s * stride4];
        a.x += b.x; a.y += b.y; a.z += b.z; a.w += b.w;
    }
    ((float4*)dst)[i] = a;
}

// ---------------- qkv MFMA GEMM with split epilogue ------------------------
// gb[8192][512] @ Wqkv^T + bqkv -> qb/kb bf16 [8192][512], vb bf16 [8192][512]
__global__ __launch_bounds__(256) void mgemm_qkv_k(
    const unsigned short* __restrict__ A, const unsigned short* __restrict__ B,
    const float* __restrict__ bias,
    unsigned short* __restrict__ qb, unsigned short* __restrict__ kb,
    unsigned short* __restrict__ vb)
{
    constexpr int BM = 128, BN = 128, BK = 32;
    __shared__ unsigned short sA[BM * BK];
    __shared__ unsigned short sB[BN * BK];
    const int t = threadIdx.x, lane = t & 63, w = t >> 6;
    const int wr = w >> 1, wc = w & 1;
    const int fr = lane & 15, fq = lane >> 4;
    const int bm = blockIdx.y * BM, bn = blockIdx.x * BN;

    f32x4 acc[4][4];
    #pragma unroll
    for (int m = 0; m < 4; m++)
        #pragma unroll
        for (int n = 0; n < 4; n++)
            #pragma unroll
            for (int r = 0; r < 4; r++) acc[m][n][r] = 0.f;

    for (int k0 = 0; k0 < 512; k0 += BK) {
        __syncthreads();
        #pragma unroll
        for (int i = 0; i < 2; i++) {
            int slot = i * 256 + t;
            __builtin_amdgcn_global_load_lds(
                (const __attribute__((address_space(1))) unsigned int*)
                    (A + (size_t)(bm + (slot >> 2)) * 512 + k0 + (slot & 3) * 8),
                (__attribute__((address_space(3))) unsigned int*)
                    (sA + (i * 256 + w * 64) * 8), 16, 0, 0);
            __builtin_amdgcn_global_load_lds(
                (const __attribute__((address_space(1))) unsigned int*)
                    (B + (size_t)(bn + (slot >> 2)) * 512 + k0 + (slot & 3) * 8),
                (__attribute__((address_space(3))) unsigned int*)
                    (sB + (i * 256 + w * 64) * 8), 16, 0, 0);
        }
        __syncthreads();
        s16x8 a[4], b[4];
        #pragma unroll
        for (int m = 0; m < 4; m++)
            a[m] = *(const s16x8*)&sA[(wr * 64 + m * 16 + fr) * BK + fq * 8];
        #pragma unroll
        for (int n = 0; n < 4; n++)
            b[n] = *(const s16x8*)&sB[(wc * 64 + n * 16 + fr) * BK + fq * 8];
        #pragma unroll
        for (int m = 0; m < 4; m++)
            #pragma unroll
            for (int n = 0; n < 4; n++)
                acc[m][n] = __builtin_amdgcn_mfma_f32_16x16x32_bf16(a[m], b[n], acc[m][n], 0, 0, 0);
    }

    #pragma unroll
    for (int m = 0; m < 4; m++) {
        const int row = bm + wr * 64 + m * 16 + fq * 4;
        #pragma unroll
        for (int n = 0; n < 4; n++) {
            const int col = bn + wc * 64 + n * 16 + fr;
            const float bv = bias[col];
            #pragma unroll
            for (int r = 0; r < 4; r++) {
                float v = acc[m][n][r] + bv;
                unsigned short u = f2bf(v);
                if (col < 512)       qb[(size_t)(row + r) * 512 + col] = u;
                else if (col < 1024) kb[(size_t)(row + r) * 512 + (col - 512)] = u;
                else                 vb[(size_t)(row + r) * 512 + (col - 1024)] = u;
            }
        }
    }
}

// ---------------- bf16 transpose: vb[8192][512] -> vT[512][8192] ------------
__global__ __launch_bounds__(256) void trT_k(const unsigned short* __restrict__ vb,
                                             unsigned short* __restrict__ vT) {
    __shared__ unsigned short s[64][65];
    const int t = threadIdx.x;
    const int rowo = blockIdx.y * 64;     // vb row tile (0..127)
    const int colo = blockIdx.x * 64;     // vb col tile (0..7)
    {
        int r = t >> 2, cg = (t & 3) * 16;
        const s16x8* src = (const s16x8*)(vb + (size_t)(rowo + r) * 512 + colo + cg);
        s16x8 u0 = src[0], u1 = src[1];
        #pragma unroll
        for (int j = 0; j < 8; j++) {
            s[r][cg + j]     = (unsigned short)u0[j];
            s[r][cg + 8 + j] = (unsigned short)u1[j];
        }
    }
    __syncthreads();
    {
        int c = t >> 2, rg = (t & 3) * 16;
        s16x8 o0, o1;
        #pragma unroll
        for (int j = 0; j < 8; j++) {
            o0[j] = (short)s[rg + j][c];
            o1[j] = (short)s[rg + 8 + j][c];
        }
        s16x8* dst = (s16x8*)(vT + (size_t)(colo + c) * 8192 + rowo + rg);
        dst[0] = o0; dst[1] = o1;
    }
}

// ---------------- per-node attention dots (wave per node) -------------------
__global__ __launch_bounds__(256) void node_dots_k(
    const float* __restrict__ h, const float* __restrict__ a_src,
    const float* __restrict__ a_dst, float* __restrict__ as_, float* __restrict__ ad_)
{
    int wid  = (blockIdx.x * 256 + threadIdx.x) >> 6;
    int lane = threadIdx.x & 63;
    if (wid >= NN_) return;
    const float* hr = h + (size_t)wid * HH_;
    float s1 = 0.f, s2 = 0.f;
    #pragma unroll
    for (int j = 0; j < 8; j++) {
        float v = hr[lane + j*64];
        s1 = fmaf(v, a_src[lane + j*64], s1);
        s2 = fmaf(v, a_dst[lane + j*64], s2);
    }
    #pragma unroll
    for (int off = 32; off; off >>= 1) {
        s1 += __shfl_down(s1, off);
        s2 += __shfl_down(s2, off);
    }
    if (lane == 0) { as_[wid] = s1; ad_[wid] = s2; }
}

// ---------------- CSR build ------------------------------------------------
__global__ void count_deg_k(const int* eAB, const int* eBA, int* deg) {
    int i = blockIdx.x * 256 + threadIdx.x;
    if (i >= NE_) return;
    int s, d; edge_sd(i, eAB, eBA, s, d);
    atomicAdd(&deg[d], 1);
}

__global__ __launch_bounds__(256) void scan_k(const int* __restrict__ deg, int* rowstart) {
    __shared__ int part[256];
    int t = threadIdx.x;
    int base = t * 32;
    int loc[32]; int s = 0;
    #pragma unroll
    for (int j = 0; j < 32; j++) { loc[j] = s; s += deg[base + j]; }
    part[t] = s;
    __syncthreads();
    if (t == 0) {
        int a = 0;
        for (int i = 0; i < 256; i++) { int v = part[i]; part[i] = a; a += v; }
        rowstart[NN_] = a;
    }
    __syncthreads();
    int off = part[t];
    #pragma unroll
    for (int j = 0; j < 32; j++) rowstart[base + j] = off + loc[j];
}

__global__ void fill_csr_k(const int* eAB, const int* eBA,
                           const int* __restrict__ rowstart, int* cursor, int* csr) {
    int i = blockIdx.x * 256 + threadIdx.x;
    if (i >= NE_) return;
    int s, d; edge_sd(i, eAB, eBA, s, d);
    int pos = atomicAdd(&cursor[d], 1);
    csr[rowstart[d] + pos] = i;
}

// ---------------- GAT edge passes ------------------------------------------
__global__ void edge_pass1_k(const int* eAB, const int* eBA,
                             const float* __restrict__ as_, const float* __restrict__ ad_,
                             float* evals, unsigned* mkey) {
    int i = blockIdx.x * 256 + threadIdx.x;
    if (i >= NE_) return;
    int s, d; edge_sd(i, eAB, eBA, s, d);
    float e = as_[s] + ad_[d];
    e = (e >= 0.f) ? e : NEG_SLOPE_ * e;
    evals[i] = e;
    atomicMax(&mkey[d], fkey(e));
}

__global__ void edge_pass2_k(const int* eAB, const int* eBA,
                             const unsigned* __restrict__ mkey,
                             float* evals, float* denom) {
    int i = blockIdx.x * 256 + threadIdx.x;
    if (i >= NE_) return;
    int s, d; edge_sd(i, eAB, eBA, s, d);
    float m = finv(mkey[d]);
    float ex = expf(evals[i] - m);
    evals[i] = ex;
    atomicAdd(&denom[d], ex);
}

// ---------------- GAT aggregation (CSR gather, wave per node) ---------------
__global__ __launch_bounds__(256) void gat_agg_k(
    const int* eAB, const int* eBA,
    const int* __restrict__ rowstart, const int* __restrict__ csr,
    const float* __restrict__ evals, const float* __restrict__ denom,
    const float* __restrict__ h, const float* __restrict__ bias,
    float* __restrict__ out, int ldo)
{
    int wid  = (blockIdx.x * 256 + threadIdx.x) >> 6;
    int lane = threadIdx.x & 63;
    if (wid >= NN_) return;
    float acc[8] = {0.f,0.f,0.f,0.f,0.f,0.f,0.f,0.f};
    int beg = rowstart[wid], end = rowstart[wid + 1];
    float rden = 1.0f / denom[wid];
    for (int p = beg; p < end; p++) {
        int eid = csr[p];
        int s, d; edge_sd(eid, eAB, eBA, s, d);
        float alpha = evals[eid] * rden;
        const float* hr = h + (size_t)s * HH_;
        #pragma unroll
        for (int j = 0; j < 8; j++) acc[j] = fmaf(alpha, hr[lane + j*64], acc[j]);
    }
    float* o = out + (size_t)wid * ldo;
    #pragma unroll
    for (int j = 0; j < 8; j++) o[lane + j*64] = acc[j] + bias[lane + j*64];
}

// ---------------- bf16 row softmax over 8192 columns (in place) ------------
__global__ __launch_bounds__(256) void softmax_bf16_k(unsigned short* __restrict__ S,
                                                      float scale) {
    __shared__ float red[8];
    const int row = blockIdx.x, t = threadIdx.x;
    uint4* rp = (uint4*)(S + (size_t)row * 8192);
    float v[32];
    uint4 u[4];
    float mx = -3.0e38f;
    #pragma unroll
    for (int i = 0; i < 4; i++) {
        u[i] = rp[t + i * 256];
        const unsigned* uw = (const unsigned*)&u[i];
        #pragma unroll
        for (int j = 0; j < 4; j++) {
            float lo = __uint_as_float(uw[j] << 16) * scale;
            float hi = __uint_as_float(uw[j] & 0xffff0000u) * scale;
            v[i*8 + 2*j]     = lo;
            v[i*8 + 2*j + 1] = hi;
            mx = fmaxf(mx, fmaxf(lo, hi));
        }
    }
    #pragma unroll
    for (int o = 32; o; o >>= 1) mx = fmaxf(mx, __shfl_down(mx, o));
    if ((t & 63) == 0) red[t >> 6] = mx;
    __syncthreads();
    mx = fmaxf(fmaxf(red[0], red[1]), fmaxf(red[2], red[3]));
    float sum = 0.f;
    #pragma unroll
    for (int i = 0; i < 32; i++) { float p = expf(v[i] - mx); v[i] = p; sum += p; }
    #pragma unroll
    for (int o = 32; o; o >>= 1) sum += __shfl_down(sum, o);
    if ((t & 63) == 0) red[4 + (t >> 6)] = sum;
    __syncthreads();
    const float rs = 1.0f / (red[4] + red[5] + red[6] + red[7]);
    #pragma unroll
    for (int i = 0; i < 4; i++) {
        unsigned* uw = (unsigned*)&u[i];
        #pragma unroll
        for (int j = 0; j < 4; j++)
            uw[j] = (unsigned)f2bf(v[i*8 + 2*j] * rs)
                  | ((unsigned)f2bf(v[i*8 + 2*j + 1] * rs) << 16);
        rp[t + i * 256] = u[i];
    }
}

// ---------------- flush one 512-col half into the f32 output ----------------
__global__ __launch_bounds__(256) void store_half_k(
    const float* __restrict__ src, float* __restrict__ out, int col0)
{
    int i = blockIdx.x * 256 + threadIdx.x;
    if (i >= NN_ * 512) return;
    int node = i >> 9, c = i & 511;
    out[(size_t)node * 1024 + col0 + c] = src[i];
}

// ===========================================================================
extern "C" void kernel_launch(void* const* d_in, const int* in_sizes, int n_in,
                              void* d_out, int out_size, void* d_ws, size_t ws_size,
                              hipStream_t stream)
{
    const float* x_A    = (const float*)d_in[0];
    const float* x_B    = (const float*)d_in[1];
    const int*   eAB    = (const int*)d_in[2];
    const int*   eBA    = (const int*)d_in[3];
    const float* W_inA  = (const float*)d_in[4];  const float* b_inA  = (const float*)d_in[5];
    const float* W_inB  = (const float*)d_in[6];  const float* b_inB  = (const float*)d_in[7];
    const float* W_in2A = (const float*)d_in[8];  const float* b_in2A = (const float*)d_in[9];
    const float* W_in2B = (const float*)d_in[10]; const float* b_in2B = (const float*)d_in[11];
    const float* Wg1    = (const float*)d_in[12]; const float* a_src1 = (const float*)d_in[13];
    const float* a_dst1 = (const float*)d_in[14]; const float* bg1    = (const float*)d_in[15];
    const float* Wg2    = (const float*)d_in[16]; const float* a_src2 = (const float*)d_in[17];
    const float* a_dst2 = (const float*)d_in[18]; const float* bg2    = (const float*)d_in[19];
    const float* Wqkv   = (const float*)d_in[20]; const float* bqkv   = (const float*)d_in[21];
    const float* Wo     = (const float*)d_in[22]; const float* bo     = (const float*)d_in[23];

    float* out = (float*)d_out;

    char* base = (char*)d_ws;
    size_t off = 0;
    auto alloc = [&](size_t nb) -> char* {
        char* p = base + off;
        off = (off + nb + 255) & ~(size_t)255;
        return p;
    };

    float*          bufA  = (float*)alloc((size_t)NN_ * 512 * 4);
    float*          bufB  = (float*)alloc((size_t)NN_ * 512 * 4);
    float*          bufC  = (float*)alloc((size_t)NN_ * 512 * 4);   // also PV partials
    float*          as_   = (float*)alloc(NN_ * 4);
    float*          ad_   = (float*)alloc(NN_ * 4);
    unsigned*       mkey  = (unsigned*)alloc(NN_ * 4);
    float*          denom = (float*)alloc(NN_ * 4);
    float*          evals = (float*)alloc((size_t)NE_ * 4);
    int*            deg   = (int*)alloc(NN_ * 4);
    int*            rowst = (int*)alloc((NN_ + 1) * 4);
    int*            cursor= (int*)alloc(NN_ * 4);
    int*            csr   = (int*)alloc((size_t)NE_ * 4);
    unsigned short* xbA   = (unsigned short*)alloc((size_t)NA_ * 256 * 2);
    unsigned short* xbB   = (unsigned short*)alloc((size_t)NB_ * 256 * 2);
    unsigned short* WbinA = (unsigned short*)alloc((size_t)512 * 256 * 2);
    unsigned short* WbinB = (unsigned short*)alloc((size_t)512 * 256 * 2);
    unsigned short* Wbin2A= (unsigned short*)alloc((size_t)512 * 256 * 2);
    unsigned short* Wbin2B= (unsigned short*)alloc((size_t)512 * 256 * 2);
    unsigned short* Wbqkv = (unsigned short*)alloc((size_t)1536 * 512 * 2);
    unsigned short* Wbo   = (unsigned short*)alloc((size_t)512 * 512 * 2);
    unsigned short* Wg1hi = (unsigned short*)alloc((size_t)512 * 512 * 2);
    unsigned short* Wg1lo = (unsigned short*)alloc((size_t)512 * 512 * 2);
    unsigned short* Wg2hi = (unsigned short*)alloc((size_t)512 * 512 * 2);
    unsigned short* Wg2lo = (unsigned short*)alloc((size_t)512 * 512 * 2);
    unsigned short* qb    = (unsigned short*)alloc((size_t)NN_ * 512 * 2);  // also Ahi
    unsigned short* kb    = (unsigned short*)alloc((size_t)NN_ * 512 * 2);  // also Alo
    unsigned short* vT    = (unsigned short*)alloc((size_t)512 * NN_ * 2);

    // score-chunk buffer (bf16): largest R that fits
    int R;
    if (off + (size_t)2048 * 8192 * 2 <= ws_size)      R = 2048;
    else if (off + (size_t)1024 * 8192 * 2 <= ws_size) R = 1024;
    else                                               R = 512;
    unsigned short* Sb = (unsigned short*)alloc((size_t)R * 8192 * 2);
    const int SEGS = 4 * (2048 / R);            // 4/8/16 -> pbuf 16MB = bufC
    const int KSEG = 8192 / SEGS;

    // overlays inside bufA (free after local store_half):
    unsigned short* gb = (unsigned short*)bufA;                  // [0, 8MB)
    unsigned short* vb = gb + (size_t)NN_ * 512;                 // [8MB, 16MB)
    unsigned short* ab = vb;                                     // reused after PV loop

    const int EG = (NE_ + 255) / 256;
    const float scale = 0.044194173824159216f;  // 1/sqrt(512)

    // -------- weight / input casts -----------------------------------------
    auto cvtb = [&](const float* s, unsigned short* d, int n) {
        cvtb_k<<<(n/4 + 255) / 256, 256, 0, stream>>>(s, d, n / 4);
    };
    cvtb(x_A,    xbA,    NA_ * 256);
    cvtb(x_B,    xbB,    NB_ * 256);
    cvtb(W_inA,  WbinA,  512 * 256);
    cvtb(W_inB,  WbinB,  512 * 256);
    cvtb(W_in2A, Wbin2A, 512 * 256);
    cvtb(W_in2B, Wbin2B, 512 * 256);
    cvtb(Wqkv,   Wbqkv,  1536 * 512);
    cvtb(Wo,     Wbo,    512 * 512);
    csplit_k<<<(512*512/4 + 255)/256, 256, 0, stream>>>(Wg1, Wg1hi, Wg1lo, 512*512/4);
    csplit_k<<<(512*512/4 + 255)/256, 256, 0, stream>>>(Wg2, Wg2hi, Wg2lo, 512*512/4);

    // -------- CSR build -----------------------------------------------------
    hipMemsetAsync(deg, 0, NN_ * 4, stream);
    count_deg_k<<<EG, 256, 0, stream>>>(eAB, eBA, deg);
    scan_k<<<1, 256, 0, stream>>>(deg, rowst);
    hipMemsetAsync(cursor, 0, NN_ * 4, stream);
    fill_csr_k<<<EG, 256, 0, stream>>>(eAB, eBA, rowst, cursor, csr);

    // -------- local branch --------------------------------------------------
    mgemm_k<128,128,true,float><<<dim3(4, 32), 256, 0, stream>>>(
        xbA, WbinA, b_inA, bufA, 256, 256, 256, 512);
    mgemm_k<128,128,true,float><<<dim3(4, 32), 256, 0, stream>>>(
        xbB, WbinB, b_inB, bufA + (size_t)4096*512, 256, 256, 256, 512);
    // GAT layer 1 (split-precision MFMA, ~f32 accurate)
    csplit_k<<<(NN_*512/4 + 255)/256, 256, 0, stream>>>(bufA, qb, kb, NN_*512/4);
    mgemm3_k<<<dim3(4, 64), 256, 0, stream>>>(qb, kb, Wg1hi, Wg1lo, bufB,
                                              512, 512, 512, 512);
    node_dots_k<<<NN_/4, 256, 0, stream>>>(bufB, a_src1, a_dst1, as_, ad_);
    hipMemsetAsync(mkey, 0, NN_ * 4, stream);
    hipMemsetAsync(denom, 0, NN_ * 4, stream);
    edge_pass1_k<<<EG, 256, 0, stream>>>(eAB, eBA, as_, ad_, evals, mkey);
    edge_pass2_k<<<EG, 256, 0, stream>>>(eAB, eBA, mkey, evals, denom);
    gat_agg_k<<<NN_/4, 256, 0, stream>>>(eAB, eBA, rowst, csr, evals, denom,
                                         bufB, bg1, bufC, 512);
    // GAT layer 2
    csplit_k<<<(NN_*512/4 + 255)/256, 256, 0, stream>>>(bufC, qb, kb, NN_*512/4);
    mgemm3_k<<<dim3(4, 64), 256, 0, stream>>>(qb, kb, Wg2hi, Wg2lo, bufB,
                                              512, 512, 512, 512);
    node_dots_k<<<NN_/4, 256, 0, stream>>>(bufB, a_src2, a_dst2, as_, ad_);
    hipMemsetAsync(mkey, 0, NN_ * 4, stream);
    hipMemsetAsync(denom, 0, NN_ * 4, stream);
    edge_pass1_k<<<EG, 256, 0, stream>>>(eAB, eBA, as_, ad_, evals, mkey);
    edge_pass2_k<<<EG, 256, 0, stream>>>(eAB, eBA, mkey, evals, denom);
    gat_agg_k<<<NN_/4, 256, 0, stream>>>(eAB, eBA, rowst, csr, evals, denom,
                                         bufB, bg2, bufA, 512);
    store_half_k<<<(NN_*512)/256, 256, 0, stream>>>(bufA, out, 0);  // frees bufA

    // -------- global branch -------------------------------------------------
    mgemm_k<128,128,true,float><<<dim3(4, 32), 256, 0, stream>>>(
        xbA, Wbin2A, b_in2A, bufC, 256, 256, 256, 512);
    mgemm_k<128,128,true,float><<<dim3(4, 32), 256, 0, stream>>>(
        xbB, Wbin2B, b_in2B, bufC + (size_t)4096*512, 256, 256, 256, 512);
    cvtb(bufC, gb, NN_ * 512);                       // g -> bf16 (bufA lo half)
    mgemm_qkv_k<<<dim3(12, 64), 256, 0, stream>>>(gb, Wbqkv, bqkv, qb, kb, vb);
    trT_k<<<dim3(8, 128), 256, 0, stream>>>(vb, vT); // coalesced V transpose
    for (int c0 = 0; c0 < 8192; c0 += R) {
        mgemm_k<128,128,false,unsigned short><<<dim3(64, R/128), 256, 0, stream>>>(
            qb + (size_t)c0 * 512, kb, nullptr, Sb, 512, 512, 512, 8192);
        softmax_bf16_k<<<R, 256, 0, stream>>>(Sb, scale);
        mgemm_pv_k<<<dim3(4, R/128, SEGS), 256, 0, stream>>>(
            Sb, vT, bufC, KSEG, (size_t)R * 512);
        radd_k<<<(R*512/4 + 255)/256, 256, 0, stream>>>(
            bufC, bufB + (size_t)c0 * 512, R*512/4, SEGS, (size_t)R*512/4);
    }
    cvtb(bufB, ab, NN_ * 512);                       // attnO -> bf16 (bufA hi half)
    mgemm_k<128,128,true,float><<<dim3(4, 64), 256, 0, stream>>>(
        ab, Wbo, bo, bufC, 512, 512, 512, 512);
    store_half_k<<<(NN_*512)/256, 256, 0, stream>>>(bufC, out, 512);
}

// Round 9
// 761.451 us; speedup vs baseline: 9.1907x; 1.1246x over previous
//
#include <hip/hip_runtime.h>
#include <hip/hip_bf16.h>

#define NA_ 4096
#define NB_ 4096
#define NN_ 8192            // total nodes
#define EE_ 131072          // edges per direction
#define NE_ (2*EE_ + NN_)   // homogeneous edges incl. self loops = 270336
#define HH_ 512
#define NEG_SLOPE_ 0.2f

typedef __attribute__((ext_vector_type(4))) float f32x4;
typedef __attribute__((ext_vector_type(8))) short s16x8;

__device__ inline unsigned short f2bf(float v) {
    __hip_bfloat16 h = __float2bfloat16(v);
    return __builtin_bit_cast(unsigned short, h);
}
__device__ inline float bf2f(unsigned short u) {
    return __uint_as_float(((unsigned)u) << 16);
}

// ---------------- float-order <-> unsigned-order mapping for atomic max ----
__device__ inline unsigned fkey(float f) {
    unsigned b = __float_as_uint(f);
    return (b & 0x80000000u) ? ~b : (b | 0x80000000u);
}
__device__ inline float finv(unsigned k) {
    return (k & 0x80000000u) ? __uint_as_float(k & 0x7fffffffu)
                             : __uint_as_float(~k);
}

// ---------------- homogeneous edge id -> (src, dst) ------------------------
__device__ inline void edge_sd(int i, const int* __restrict__ eAB,
                               const int* __restrict__ eBA, int& s, int& d) {
    if (i < EE_)            { s = eAB[i];            d = eAB[EE_ + i] + NA_; }
    else if (i < 2 * EE_)   { int j = i - EE_; s = eBA[j] + NA_; d = eBA[EE_ + j]; }
    else                    { s = i - 2 * EE_;       d = s; }
}

// ---------------- f32 -> bf16 cast (vectorized) ----------------------------
__global__ __launch_bounds__(256) void cvtb_k(const float* __restrict__ s,
                                              unsigned short* __restrict__ d, int n4) {
    int i = blockIdx.x * 256 + threadIdx.x;
    if (i >= n4) return;
    float4 v = ((const float4*)s)[i];
    ushort4 o;
    o.x = f2bf(v.x); o.y = f2bf(v.y); o.z = f2bf(v.z); o.w = f2bf(v.w);
    ((ushort4*)d)[i] = o;
}

// ---------------- f32 -> (bf16 hi, bf16 lo) split cast ---------------------
__global__ __launch_bounds__(256) void csplit_k(const float* __restrict__ s,
                                                unsigned short* __restrict__ hi,
                                                unsigned short* __restrict__ lo, int n4) {
    int i = blockIdx.x * 256 + threadIdx.x;
    if (i >= n4) return;
    float4 v = ((const float4*)s)[i];
    ushort4 h, l;
    h.x = f2bf(v.x); l.x = f2bf(v.x - bf2f(h.x));
    h.y = f2bf(v.y); l.y = f2bf(v.y - bf2f(h.y));
    h.z = f2bf(v.z); l.z = f2bf(v.z - bf2f(h.z));
    h.w = f2bf(v.w); l.w = f2bf(v.w - bf2f(h.w));
    ((ushort4*)hi)[i] = h;
    ((ushort4*)lo)[i] = l;
}

// ---------------- MFMA bf16 GEMM: C[M,N] = A @ B^T (+bias) -----------------
template<int BM, int BN, bool BIAS, typename OutT>
__global__ __launch_bounds__(256) void mgemm_k(
    const unsigned short* __restrict__ A, const unsigned short* __restrict__ B,
    const float* __restrict__ bias, OutT* __restrict__ C,
    int K, int lda, int ldb, int ldc)
{
    constexpr int BK = 32;
    constexpr int WM = BM / 2, WN = BN / 2;
    constexpr int AM = WM / 16, AN = WN / 16;
    constexpr int AISS = BM * 4 / 256, BISS = BN * 4 / 256;
    __shared__ unsigned short sA[BM * BK];
    __shared__ unsigned short sB[BN * BK];
    const int t = threadIdx.x, lane = t & 63, w = t >> 6;
    const int wr = w >> 1, wc = w & 1;
    const int fr = lane & 15, fq = lane >> 4;
    const int bm = blockIdx.y * BM, bn = blockIdx.x * BN;

    f32x4 acc[AM][AN];
    #pragma unroll
    for (int m = 0; m < AM; m++)
        #pragma unroll
        for (int n = 0; n < AN; n++)
            #pragma unroll
            for (int r = 0; r < 4; r++) acc[m][n][r] = 0.f;

    for (int k0 = 0; k0 < K; k0 += BK) {
        __syncthreads();
        #pragma unroll
        for (int i = 0; i < AISS; i++) {
            int slot = i * 256 + t;
            __builtin_amdgcn_global_load_lds(
                (const __attribute__((address_space(1))) unsigned int*)
                    (A + (size_t)(bm + (slot >> 2)) * lda + k0 + (slot & 3) * 8),
                (__attribute__((address_space(3))) unsigned int*)
                    (sA + (i * 256 + w * 64) * 8), 16, 0, 0);
        }
        #pragma unroll
        for (int i = 0; i < BISS; i++) {
            int slot = i * 256 + t;
            __builtin_amdgcn_global_load_lds(
                (const __attribute__((address_space(1))) unsigned int*)
                    (B + (size_t)(bn + (slot >> 2)) * ldb + k0 + (slot & 3) * 8),
                (__attribute__((address_space(3))) unsigned int*)
                    (sB + (i * 256 + w * 64) * 8), 16, 0, 0);
        }
        __syncthreads();
        s16x8 a[AM], b[AN];
        #pragma unroll
        for (int m = 0; m < AM; m++)
            a[m] = *(const s16x8*)&sA[(wr * WM + m * 16 + fr) * BK + fq * 8];
        #pragma unroll
        for (int n = 0; n < AN; n++)
            b[n] = *(const s16x8*)&sB[(wc * WN + n * 16 + fr) * BK + fq * 8];
        #pragma unroll
        for (int m = 0; m < AM; m++)
            #pragma unroll
            for (int n = 0; n < AN; n++)
                acc[m][n] = __builtin_amdgcn_mfma_f32_16x16x32_bf16(a[m], b[n], acc[m][n], 0, 0, 0);
    }

    // C/D layout: col = lane&15, row = (lane>>4)*4 + reg
    #pragma unroll
    for (int m = 0; m < AM; m++) {
        const int row = bm + wr * WM + m * 16 + fq * 4;
        #pragma unroll
        for (int n = 0; n < AN; n++) {
            const int col = bn + wc * WN + n * 16 + fr;
            const float bv = BIAS ? bias[col] : 0.f;
            #pragma unroll
            for (int r = 0; r < 4; r++) {
                float v = acc[m][n][r] + bv;
                if constexpr (sizeof(OutT) == 2)
                    C[(size_t)(row + r) * ldc + col] = (OutT)f2bf(v);
                else
                    C[(size_t)(row + r) * ldc + col] = v;
            }
        }
    }
}

// ---------------- merged per-type input linear (A rows 0..4095, B rows 4096+)
// SPLIT: write hi/lo bf16 pair; else write bf16 only (o1).
// M=8192, N=512, K=256 fixed; grid (4,64).
template<bool SPLIT>
__global__ __launch_bounds__(256) void mgemm_in_k(
    const unsigned short* __restrict__ xA, const unsigned short* __restrict__ xB,
    const unsigned short* __restrict__ WA, const unsigned short* __restrict__ WB,
    const float* __restrict__ biasA, const float* __restrict__ biasB,
    unsigned short* __restrict__ o1, unsigned short* __restrict__ o2)
{
    constexpr int BK = 32;
    __shared__ unsigned short sA[128 * BK];
    __shared__ unsigned short sB[128 * BK];
    const int t = threadIdx.x, lane = t & 63, w = t >> 6;
    const int wr = w >> 1, wc = w & 1;
    const int fr = lane & 15, fq = lane >> 4;
    const int bm = blockIdx.y * 128, bn = blockIdx.x * 128;
    const bool isB = bm >= NA_;
    const unsigned short* A = isB ? xB : xA;
    const unsigned short* W = isB ? WB : WA;
    const float* bias = isB ? biasB : biasA;
    const int bml = bm - (isB ? NA_ : 0);

    f32x4 acc[4][4];
    #pragma unroll
    for (int m = 0; m < 4; m++)
        #pragma unroll
        for (int n = 0; n < 4; n++)
            #pragma unroll
            for (int r = 0; r < 4; r++) acc[m][n][r] = 0.f;

    for (int k0 = 0; k0 < 256; k0 += BK) {
        __syncthreads();
        #pragma unroll
        for (int i = 0; i < 2; i++) {
            int slot = i * 256 + t;
            __builtin_amdgcn_global_load_lds(
                (const __attribute__((address_space(1))) unsigned int*)
                    (A + (size_t)(bml + (slot >> 2)) * 256 + k0 + (slot & 3) * 8),
                (__attribute__((address_space(3))) unsigned int*)
                    (sA + (i * 256 + w * 64) * 8), 16, 0, 0);
            __builtin_amdgcn_global_load_lds(
                (const __attribute__((address_space(1))) unsigned int*)
                    (W + (size_t)(bn + (slot >> 2)) * 256 + k0 + (slot & 3) * 8),
                (__attribute__((address_space(3))) unsigned int*)
                    (sB + (i * 256 + w * 64) * 8), 16, 0, 0);
        }
        __syncthreads();
        s16x8 a[4], b[4];
        #pragma unroll
        for (int m = 0; m < 4; m++)
            a[m] = *(const s16x8*)&sA[(wr * 64 + m * 16 + fr) * BK + fq * 8];
        #pragma unroll
        for (int n = 0; n < 4; n++)
            b[n] = *(const s16x8*)&sB[(wc * 64 + n * 16 + fr) * BK + fq * 8];
        #pragma unroll
        for (int m = 0; m < 4; m++)
            #pragma unroll
            for (int n = 0; n < 4; n++)
                acc[m][n] = __builtin_amdgcn_mfma_f32_16x16x32_bf16(a[m], b[n], acc[m][n], 0, 0, 0);
    }

    #pragma unroll
    for (int m = 0; m < 4; m++) {
        const int row = bm + wr * 64 + m * 16 + fq * 4;
        #pragma unroll
        for (int n = 0; n < 4; n++) {
            const int col = bn + wc * 64 + n * 16 + fr;
            const float bv = bias[col];
            #pragma unroll
            for (int r = 0; r < 4; r++) {
                float v = acc[m][n][r] + bv;
                unsigned short hi = f2bf(v);
                o1[(size_t)(row + r) * 512 + col] = hi;
                if (SPLIT)
                    o2[(size_t)(row + r) * 512 + col] = f2bf(v - bf2f(hi));
            }
        }
    }
}

// ---------------- split-precision MFMA GEMM (~f32 accuracy) ----------------
// C = (Ahi+Alo) @ (Bhi+Blo)^T dropping lo*lo; also emits bf16 copy Cb.
__global__ __launch_bounds__(256) void mgemm3_k(
    const unsigned short* __restrict__ Ahi, const unsigned short* __restrict__ Alo,
    const unsigned short* __restrict__ Bhi, const unsigned short* __restrict__ Blo,
    float* __restrict__ C, unsigned short* __restrict__ Cb,
    int K, int lda, int ldb, int ldc)
{
    constexpr int BM = 128, BN = 128, BK = 32;
    __shared__ unsigned short sAh[BM * BK], sAl[BM * BK];
    __shared__ unsigned short sBh[BN * BK], sBl[BN * BK];
    const int t = threadIdx.x, lane = t & 63, w = t >> 6;
    const int wr = w >> 1, wc = w & 1;
    const int fr = lane & 15, fq = lane >> 4;
    const int bm = blockIdx.y * BM, bn = blockIdx.x * BN;

    f32x4 acc[4][4];
    #pragma unroll
    for (int m = 0; m < 4; m++)
        #pragma unroll
        for (int n = 0; n < 4; n++)
            #pragma unroll
            for (int r = 0; r < 4; r++) acc[m][n][r] = 0.f;

    for (int k0 = 0; k0 < K; k0 += BK) {
        __syncthreads();
        #pragma unroll
        for (int i = 0; i < 2; i++) {
            int slot = i * 256 + t;
            size_t ga = (size_t)(bm + (slot >> 2)) * lda + k0 + (slot & 3) * 8;
            size_t gb = (size_t)(bn + (slot >> 2)) * ldb + k0 + (slot & 3) * 8;
            unsigned loff = (unsigned)(i * 256 + w * 64) * 8;
            __builtin_amdgcn_global_load_lds(
                (const __attribute__((address_space(1))) unsigned int*)(Ahi + ga),
                (__attribute__((address_space(3))) unsigned int*)(sAh + loff), 16, 0, 0);
            __builtin_amdgcn_global_load_lds(
                (const __attribute__((address_space(1))) unsigned int*)(Alo + ga),
                (__attribute__((address_space(3))) unsigned int*)(sAl + loff), 16, 0, 0);
            __builtin_amdgcn_global_load_lds(
                (const __attribute__((address_space(1))) unsigned int*)(Bhi + gb),
                (__attribute__((address_space(3))) unsigned int*)(sBh + loff), 16, 0, 0);
            __builtin_amdgcn_global_load_lds(
                (const __attribute__((address_space(1))) unsigned int*)(Blo + gb),
                (__attribute__((address_space(3))) unsigned int*)(sBl + loff), 16, 0, 0);
        }
        __syncthreads();
        s16x8 ah[4], al[4], bh[4], bl[4];
        #pragma unroll
        for (int m = 0; m < 4; m++) {
            int o = (wr * 64 + m * 16 + fr) * BK + fq * 8;
            ah[m] = *(const s16x8*)&sAh[o];
            al[m] = *(const s16x8*)&sAl[o];
        }
        #pragma unroll
        for (int n = 0; n < 4; n++) {
            int o = (wc * 64 + n * 16 + fr) * BK + fq * 8;
            bh[n] = *(const s16x8*)&sBh[o];
            bl[n] = *(const s16x8*)&sBl[o];
        }
        #pragma unroll
        for (int m = 0; m < 4; m++)
            #pragma unroll
            for (int n = 0; n < 4; n++) {
                acc[m][n] = __builtin_amdgcn_mfma_f32_16x16x32_bf16(ah[m], bh[n], acc[m][n], 0, 0, 0);
                acc[m][n] = __builtin_amdgcn_mfma_f32_16x16x32_bf16(ah[m], bl[n], acc[m][n], 0, 0, 0);
                acc[m][n] = __builtin_amdgcn_mfma_f32_16x16x32_bf16(al[m], bh[n], acc[m][n], 0, 0, 0);
            }
    }

    #pragma unroll
    for (int m = 0; m < 4; m++) {
        const int row = bm + wr * 64 + m * 16 + fq * 4;
        #pragma unroll
        for (int n = 0; n < 4; n++) {
            const int col = bn + wc * 64 + n * 16 + fr;
            #pragma unroll
            for (int r = 0; r < 4; r++) {
                float v = acc[m][n][r];
                C[(size_t)(row + r) * ldc + col]  = v;
                Cb[(size_t)(row + r) * 512 + col] = f2bf(v);
            }
        }
    }
}

// ---------------- PV split-K MFMA GEMM -------------------------------------
__global__ __launch_bounds__(256) void mgemm_pv_k(
    const unsigned short* __restrict__ A, const unsigned short* __restrict__ B,
    float* __restrict__ C, int kseg, size_t segstride)
{
    constexpr int BM = 128, BN = 128, BK = 32;
    __shared__ unsigned short sA[BM * BK];
    __shared__ unsigned short sB[BN * BK];
    const int t = threadIdx.x, lane = t & 63, w = t >> 6;
    const int wr = w >> 1, wc = w & 1;
    const int fr = lane & 15, fq = lane >> 4;
    const int bm = blockIdx.y * BM, bn = blockIdx.x * BN;
    const int kofs = blockIdx.z * kseg;

    f32x4 acc[4][4];
    #pragma unroll
    for (int m = 0; m < 4; m++)
        #pragma unroll
        for (int n = 0; n < 4; n++)
            #pragma unroll
            for (int r = 0; r < 4; r++) acc[m][n][r] = 0.f;

    for (int k0 = 0; k0 < kseg; k0 += BK) {
        __syncthreads();
        #pragma unroll
        for (int i = 0; i < 2; i++) {
            int slot = i * 256 + t;
            __builtin_amdgcn_global_load_lds(
                (const __attribute__((address_space(1))) unsigned int*)
                    (A + (size_t)(bm + (slot >> 2)) * 8192 + kofs + k0 + (slot & 3) * 8),
                (__attribute__((address_space(3))) unsigned int*)
                    (sA + (i * 256 + w * 64) * 8), 16, 0, 0);
            __builtin_amdgcn_global_load_lds(
                (const __attribute__((address_space(1))) unsigned int*)
                    (B + (size_t)(bn + (slot >> 2)) * 8192 + kofs + k0 + (slot & 3) * 8),
                (__attribute__((address_space(3))) unsigned int*)
                    (sB + (i * 256 + w * 64) * 8), 16, 0, 0);
        }
        __syncthreads();
        s16x8 a[4], b[4];
        #pragma unroll
        for (int m = 0; m < 4; m++)
            a[m] = *(const s16x8*)&sA[(wr * 64 + m * 16 + fr) * BK + fq * 8];
        #pragma unroll
        for (int n = 0; n < 4; n++)
            b[n] = *(const s16x8*)&sB[(wc * 64 + n * 16 + fr) * BK + fq * 8];
        #pragma unroll
        for (int m = 0; m < 4; m++)
            #pragma unroll
            for (int n = 0; n < 4; n++)
                acc[m][n] = __builtin_amdgcn_mfma_f32_16x16x32_bf16(a[m], b[n], acc[m][n], 0, 0, 0);
    }

    float* Cz = C + (size_t)blockIdx.z * segstride;
    #pragma unroll
    for (int m = 0; m < 4; m++) {
        const int row = bm + wr * 64 + m * 16 + fq * 4;
        #pragma unroll
        for (int n = 0; n < 4; n++) {
            const int col = bn + wc * 64 + n * 16 + fr;
            #pragma unroll
            for (int r = 0; r < 4; r++)
                Cz[(size_t)(row + r) * 512 + col] = acc[m][n][r];
        }
    }
}

// ---------------- reduce split-K partials -> bf16 --------------------------
__global__ __launch_bounds__(256) void radd_k(const float* __restrict__ src,
                                              unsigned short* __restrict__ dst,
                                              int n4, int segs, size_t stride4) {
    int i = blockIdx.x * 256 + threadIdx.x;
    if (i >= n4) return;
    float4 a = ((const float4*)src)[i];
    for (int s = 1; s < segs; s++) {
        float4 b = ((const float4*)src)[i + s * stride4];
        a.x += b.x; a.y += b.y; a.z += b.z; a.w += b.w;
    }
    ushort4 o;
    o.x = f2bf(a.x); o.y = f2bf(a.y); o.z = f2bf(a.z); o.w = f2bf(a.w);
    ((ushort4*)dst)[i] = o;
}

// ---------------- qkv MFMA GEMM with split epilogue ------------------------
__global__ __launch_bounds__(256) void mgemm_qkv_k(
    const unsigned short* __restrict__ A, const unsigned short* __restrict__ B,
    const float* __restrict__ bias,
    unsigned short* __restrict__ qb, unsigned short* __restrict__ kb,
    unsigned short* __restrict__ vb)
{
    constexpr int BM = 128, BN = 128, BK = 32;
    __shared__ unsigned short sA[BM * BK];
    __shared__ unsigned short sB[BN * BK];
    const int t = threadIdx.x, lane = t & 63, w = t >> 6;
    const int wr = w >> 1, wc = w & 1;
    const int fr = lane & 15, fq = lane >> 4;
    const int bm = blockIdx.y * BM, bn = blockIdx.x * BN;

    f32x4 acc[4][4];
    #pragma unroll
    for (int m = 0; m < 4; m++)
        #pragma unroll
        for (int n = 0; n < 4; n++)
            #pragma unroll
            for (int r = 0; r < 4; r++) acc[m][n][r] = 0.f;

    for (int k0 = 0; k0 < 512; k0 += BK) {
        __syncthreads();
        #pragma unroll
        for (int i = 0; i < 2; i++) {
            int slot = i * 256 + t;
            __builtin_amdgcn_global_load_lds(
                (const __attribute__((address_space(1))) unsigned int*)
                    (A + (size_t)(bm + (slot >> 2)) * 512 + k0 + (slot & 3) * 8),
                (__attribute__((address_space(3))) unsigned int*)
                    (sA + (i * 256 + w * 64) * 8), 16, 0, 0);
            __builtin_amdgcn_global_load_lds(
                (const __attribute__((address_space(1))) unsigned int*)
                    (B + (size_t)(bn + (slot >> 2)) * 512 + k0 + (slot & 3) * 8),
                (__attribute__((address_space(3))) unsigned int*)
                    (sB + (i * 256 + w * 64) * 8), 16, 0, 0);
        }
        __syncthreads();
        s16x8 a[4], b[4];
        #pragma unroll
        for (int m = 0; m < 4; m++)
            a[m] = *(const s16x8*)&sA[(wr * 64 + m * 16 + fr) * BK + fq * 8];
        #pragma unroll
        for (int n = 0; n < 4; n++)
            b[n] = *(const s16x8*)&sB[(wc * 64 + n * 16 + fr) * BK + fq * 8];
        #pragma unroll
        for (int m = 0; m < 4; m++)
            #pragma unroll
            for (int n = 0; n < 4; n++)
                acc[m][n] = __builtin_amdgcn_mfma_f32_16x16x32_bf16(a[m], b[n], acc[m][n], 0, 0, 0);
    }

    #pragma unroll
    for (int m = 0; m < 4; m++) {
        const int row = bm + wr * 64 + m * 16 + fq * 4;
        #pragma unroll
        for (int n = 0; n < 4; n++) {
            const int col = bn + wc * 64 + n * 16 + fr;
            const float bv = bias[col];
            #pragma unroll
            for (int r = 0; r < 4; r++) {
                float v = acc[m][n][r] + bv;
                unsigned short u = f2bf(v);
                if (col < 512)       qb[(size_t)(row + r) * 512 + col] = u;
                else if (col < 1024) kb[(size_t)(row + r) * 512 + (col - 512)] = u;
                else                 vb[(size_t)(row + r) * 512 + (col - 1024)] = u;
            }
        }
    }
}

// ---------------- bf16 transpose: vb[8192][512] -> vT[512][8192] ------------
__global__ __launch_bounds__(256) void trT_k(const unsigned short* __restrict__ vb,
                                             unsigned short* __restrict__ vT) {
    __shared__ unsigned short s[64][65];
    const int t = threadIdx.x;
    const int rowo = blockIdx.y * 64;
    const int colo = blockIdx.x * 64;
    {
        int r = t >> 2, cg = (t & 3) * 16;
        const s16x8* src = (const s16x8*)(vb + (size_t)(rowo + r) * 512 + colo + cg);
        s16x8 u0 = src[0], u1 = src[1];
        #pragma unroll
        for (int j = 0; j < 8; j++) {
            s[r][cg + j]     = (unsigned short)u0[j];
            s[r][cg + 8 + j] = (unsigned short)u1[j];
        }
    }
    __syncthreads();
    {
        int c = t >> 2, rg = (t & 3) * 16;
        s16x8 o0, o1;
        #pragma unroll
        for (int j = 0; j < 8; j++) {
            o0[j] = (short)s[rg + j][c];
            o1[j] = (short)s[rg + 8 + j][c];
        }
        s16x8* dst = (s16x8*)(vT + (size_t)(colo + c) * 8192 + rowo + rg);
        dst[0] = o0; dst[1] = o1;
    }
}

// ---------------- per-node attention dots (wave per node) -------------------
__global__ __launch_bounds__(256) void node_dots_k(
    const float* __restrict__ h, const float* __restrict__ a_src,
    const float* __restrict__ a_dst, float* __restrict__ as_, float* __restrict__ ad_)
{
    int wid  = (blockIdx.x * 256 + threadIdx.x) >> 6;
    int lane = threadIdx.x & 63;
    if (wid >= NN_) return;
    const float* hr = h + (size_t)wid * HH_;
    float s1 = 0.f, s2 = 0.f;
    #pragma unroll
    for (int j = 0; j < 8; j++) {
        float v = hr[lane + j*64];
        s1 = fmaf(v, a_src[lane + j*64], s1);
        s2 = fmaf(v, a_dst[lane + j*64], s2);
    }
    #pragma unroll
    for (int off = 32; off; off >>= 1) {
        s1 += __shfl_down(s1, off);
        s2 += __shfl_down(s2, off);
    }
    if (lane == 0) { as_[wid] = s1; ad_[wid] = s2; }
}

// ---------------- CSR build ------------------------------------------------
__global__ void count_deg_k(const int* eAB, const int* eBA, int* deg) {
    int i = blockIdx.x * 256 + threadIdx.x;
    if (i >= NE_) return;
    int s, d; edge_sd(i, eAB, eBA, s, d);
    atomicAdd(&deg[d], 1);
}

__global__ __launch_bounds__(256) void scan_k(const int* __restrict__ deg, int* rowstart) {
    __shared__ int part[256];
    int t = threadIdx.x;
    int base = t * 32;
    int loc[32]; int s = 0;
    #pragma unroll
    for (int j = 0; j < 32; j++) { loc[j] = s; s += deg[base + j]; }
    part[t] = s;
    __syncthreads();
    if (t == 0) {
        int a = 0;
        for (int i = 0; i < 256; i++) { int v = part[i]; part[i] = a; a += v; }
        rowstart[NN_] = a;
    }
    __syncthreads();
    int off = part[t];
    #pragma unroll
    for (int j = 0; j < 32; j++) rowstart[base + j] = off + loc[j];
}

__global__ void fill_csr_k(const int* eAB, const int* eBA,
                           const int* __restrict__ rowstart, int* cursor, int* csr) {
    int i = blockIdx.x * 256 + threadIdx.x;
    if (i >= NE_) return;
    int s, d; edge_sd(i, eAB, eBA, s, d);
    int pos = atomicAdd(&cursor[d], 1);
    csr[rowstart[d] + pos] = i;
}

// ---------------- GAT edge passes ------------------------------------------
__global__ void edge_pass1_k(const int* eAB, const int* eBA,
                             const float* __restrict__ as_, const float* __restrict__ ad_,
                             float* evals, unsigned* mkey) {
    int i = blockIdx.x * 256 + threadIdx.x;
    if (i >= NE_) return;
    int s, d; edge_sd(i, eAB, eBA, s, d);
    float e = as_[s] + ad_[d];
    e = (e >= 0.f) ? e : NEG_SLOPE_ * e;
    evals[i] = e;
    atomicMax(&mkey[d], fkey(e));
}

__global__ void edge_pass2_k(const int* eAB, const int* eBA,
                             const unsigned* __restrict__ mkey,
                             float* evals, float* denom) {
    int i = blockIdx.x * 256 + threadIdx.x;
    if (i >= NE_) return;
    int s, d; edge_sd(i, eAB, eBA, s, d);
    float m = finv(mkey[d]);
    float ex = expf(evals[i] - m);
    evals[i] = ex;
    atomicAdd(&denom[d], ex);
}

// ---------------- GAT aggregation (CSR gather, bf16 h, wave per node) -------
// SPLIT: write hi/lo bf16 pair; else write f32.
template<bool SPLIT>
__global__ __launch_bounds__(256) void gat_agg_k(
    const int* eAB, const int* eBA,
    const int* __restrict__ rowstart, const int* __restrict__ csr,
    const float* __restrict__ evals, const float* __restrict__ denom,
    const unsigned short* __restrict__ hb, const float* __restrict__ bias,
    float* __restrict__ outF, unsigned short* __restrict__ outHi,
    unsigned short* __restrict__ outLo)
{
    int wid  = (blockIdx.x * 256 + threadIdx.x) >> 6;
    int lane = threadIdx.x & 63;
    if (wid >= NN_) return;
    float acc[8] = {0.f,0.f,0.f,0.f,0.f,0.f,0.f,0.f};
    int beg = rowstart[wid], end = rowstart[wid + 1];
    float rden = 1.0f / denom[wid];
    for (int p = beg; p < end; p++) {
        int eid = csr[p];
        int s, d; edge_sd(eid, eAB, eBA, s, d);
        float alpha = evals[eid] * rden;
        s16x8 hv = *(const s16x8*)(hb + (size_t)s * HH_ + lane * 8);
        #pragma unroll
        for (int j = 0; j < 8; j++)
            acc[j] = fmaf(alpha, bf2f((unsigned short)hv[j]), acc[j]);
    }
    #pragma unroll
    for (int j = 0; j < 8; j++) acc[j] += bias[lane * 8 + j];
    if (SPLIT) {
        s16x8 hi, lo;
        #pragma unroll
        for (int j = 0; j < 8; j++) {
            unsigned short h = f2bf(acc[j]);
            hi[j] = (short)h;
            lo[j] = (short)f2bf(acc[j] - bf2f(h));
        }
        *(s16x8*)(outHi + (size_t)wid * HH_ + lane * 8) = hi;
        *(s16x8*)(outLo + (size_t)wid * HH_ + lane * 8) = lo;
    } else {
        float* o = outF + (size_t)wid * HH_ + lane * 8;
        *(float4*)(o)     = make_float4(acc[0], acc[1], acc[2], acc[3]);
        *(float4*)(o + 4) = make_float4(acc[4], acc[5], acc[6], acc[7]);
    }
}

// ---------------- bf16 row softmax over 8192 columns (in place) ------------
__global__ __launch_bounds__(256) void softmax_bf16_k(unsigned short* __restrict__ S,
                                                      float scale) {
    __shared__ float red[8];
    const int row = blockIdx.x, t = threadIdx.x;
    uint4* rp = (uint4*)(S + (size_t)row * 8192);
    float v[32];
    uint4 u[4];
    float mx = -3.0e38f;
    #pragma unroll
    for (int i = 0; i < 4; i++) {
        u[i] = rp[t + i * 256];
        const unsigned* uw = (const unsigned*)&u[i];
        #pragma unroll
        for (int j = 0; j < 4; j++) {
            float lo = __uint_as_float(uw[j] << 16) * scale;
            float hi = __uint_as_float(uw[j] & 0xffff0000u) * scale;
            v[i*8 + 2*j]     = lo;
            v[i*8 + 2*j + 1] = hi;
            mx = fmaxf(mx, fmaxf(lo, hi));
        }
    }
    #pragma unroll
    for (int o = 32; o; o >>= 1) mx = fmaxf(mx, __shfl_down(mx, o));
    if ((t & 63) == 0) red[t >> 6] = mx;
    __syncthreads();
    mx = fmaxf(fmaxf(red[0], red[1]), fmaxf(red[2], red[3]));
    float sum = 0.f;
    #pragma unroll
    for (int i = 0; i < 32; i++) { float p = expf(v[i] - mx); v[i] = p; sum += p; }
    #pragma unroll
    for (int o = 32; o; o >>= 1) sum += __shfl_down(sum, o);
    if ((t & 63) == 0) red[4 + (t >> 6)] = sum;
    __syncthreads();
    const float rs = 1.0f / (red[4] + red[5] + red[6] + red[7]);
    #pragma unroll
    for (int i = 0; i < 4; i++) {
        unsigned* uw = (unsigned*)&u[i];
        #pragma unroll
        for (int j = 0; j < 4; j++)
            uw[j] = (unsigned)f2bf(v[i*8 + 2*j] * rs)
                  | ((unsigned)f2bf(v[i*8 + 2*j + 1] * rs) << 16);
        rp[t + i * 256] = u[i];
    }
}

// ---------------- flush one 512-col half into the f32 output ----------------
__global__ __launch_bounds__(256) void store_half_k(
    const float* __restrict__ src, float* __restrict__ out, int col0)
{
    int i = blockIdx.x * 256 + threadIdx.x;
    if (i >= NN_ * 512) return;
    int node = i >> 9, c = i & 511;
    out[(size_t)node * 1024 + col0 + c] = src[i];
}

// ===========================================================================
extern "C" void kernel_launch(void* const* d_in, const int* in_sizes, int n_in,
                              void* d_out, int out_size, void* d_ws, size_t ws_size,
                              hipStream_t stream)
{
    const float* x_A    = (const float*)d_in[0];
    const float* x_B    = (const float*)d_in[1];
    const int*   eAB    = (const int*)d_in[2];
    const int*   eBA    = (const int*)d_in[3];
    const float* W_inA  = (const float*)d_in[4];  const float* b_inA  = (const float*)d_in[5];
    const float* W_inB  = (const float*)d_in[6];  const float* b_inB  = (const float*)d_in[7];
    const float* W_in2A = (const float*)d_in[8];  const float* b_in2A = (const float*)d_in[9];
    const float* W_in2B = (const float*)d_in[10]; const float* b_in2B = (const float*)d_in[11];
    const float* Wg1    = (const float*)d_in[12]; const float* a_src1 = (const float*)d_in[13];
    const float* a_dst1 = (const float*)d_in[14]; const float* bg1    = (const float*)d_in[15];
    const float* Wg2    = (const float*)d_in[16]; const float* a_src2 = (const float*)d_in[17];
    const float* a_dst2 = (const float*)d_in[18]; const float* bg2    = (const float*)d_in[19];
    const float* Wqkv   = (const float*)d_in[20]; const float* bqkv   = (const float*)d_in[21];
    const float* Wo     = (const float*)d_in[22]; const float* bo     = (const float*)d_in[23];

    float* out = (float*)d_out;

    char* base = (char*)d_ws;
    size_t off = 0;
    auto alloc = [&](size_t nb) -> char* {
        char* p = base + off;
        off = (off + nb + 255) & ~(size_t)255;
        return p;
    };

    // bufA and bufB MUST be adjacent: Sb (32MB) spans both during attention.
    float*          bufA  = (float*)alloc((size_t)NN_ * 512 * 4);   // l2 f32 -> Sb lo half
    float*          bufB  = (float*)alloc((size_t)NN_ * 512 * 4);   // h1/h2 f32 -> Sb hi half
    float*          bufC  = (float*)alloc((size_t)NN_ * 512 * 4);   // gb+vb -> PV partials -> gout
    float*          as_   = (float*)alloc(NN_ * 4);
    float*          ad_   = (float*)alloc(NN_ * 4);
    unsigned*       mkey  = (unsigned*)alloc(NN_ * 4);  // adjacent to denom (merged memset)
    float*          denom = (float*)alloc(NN_ * 4);
    int*            deg   = (int*)alloc(NN_ * 4);       // adjacent to cursor (merged memset)
    int*            cursor= (int*)alloc(NN_ * 4);
    int*            rowst = (int*)alloc((NN_ + 1) * 4);
    float*          evals = (float*)alloc((size_t)NE_ * 4);
    int*            csr   = (int*)alloc((size_t)NE_ * 4);
    unsigned short* xbA   = (unsigned short*)alloc((size_t)NA_ * 256 * 2);
    unsigned short* xbB   = (unsigned short*)alloc((size_t)NB_ * 256 * 2);
    unsigned short* WbinA = (unsigned short*)alloc((size_t)512 * 256 * 2);
    unsigned short* WbinB = (unsigned short*)alloc((size_t)512 * 256 * 2);
    unsigned short* Wbin2A= (unsigned short*)alloc((size_t)512 * 256 * 2);
    unsigned short* Wbin2B= (unsigned short*)alloc((size_t)512 * 256 * 2);
    unsigned short* Wbqkv = (unsigned short*)alloc((size_t)1536 * 512 * 2);
    unsigned short* Wbo   = (unsigned short*)alloc((size_t)512 * 512 * 2);
    unsigned short* Wg1hi = (unsigned short*)alloc((size_t)512 * 512 * 2);
    unsigned short* Wg1lo = (unsigned short*)alloc((size_t)512 * 512 * 2);
    unsigned short* Wg2hi = (unsigned short*)alloc((size_t)512 * 512 * 2);
    unsigned short* Wg2lo = (unsigned short*)alloc((size_t)512 * 512 * 2);
    unsigned short* qb    = (unsigned short*)alloc((size_t)NN_ * 512 * 2);  // split-hi / q
    unsigned short* kb    = (unsigned short*)alloc((size_t)NN_ * 512 * 2);  // split-lo / k
    unsigned short* vT    = (unsigned short*)alloc((size_t)512 * NN_ * 2);  // also hb (local)
    unsigned short* ab    = (unsigned short*)alloc((size_t)NN_ * 512 * 2);  // attnO bf16

    // overlays
    unsigned short* hb = vT;                              // bf16 h (local branch)
    unsigned short* gb = (unsigned short*)bufC;           // g bf16 (global, pre-loop)
    unsigned short* vb = gb + (size_t)NN_ * 512;          // v bf16 (global, pre-loop)
    unsigned short* Sb = (unsigned short*)bufA;           // scores: bufA+bufB = 32MB
    float*          pv = bufC;                            // PV partials (16MB, in-loop)

    const int R = 2048, SEGS = 4, KSEG = 8192 / SEGS;
    const int EG = (NE_ + 255) / 256;
    const float scale = 0.044194173824159216f;  // 1/sqrt(512)

    // -------- casts ---------------------------------------------------------
    auto cvtb = [&](const float* s, unsigned short* d, int n) {
        cvtb_k<<<(n/4 + 255) / 256, 256, 0, stream>>>(s, d, n / 4);
    };
    cvtb(x_A,    xbA,    NA_ * 256);
    cvtb(x_B,    xbB,    NB_ * 256);
    cvtb(W_inA,  WbinA,  512 * 256);
    cvtb(W_inB,  WbinB,  512 * 256);
    cvtb(W_in2A, Wbin2A, 512 * 256);
    cvtb(W_in2B, Wbin2B, 512 * 256);
    cvtb(Wqkv,   Wbqkv,  1536 * 512);
    cvtb(Wo,     Wbo,    512 * 512);
    csplit_k<<<(512*512/4 + 255)/256, 256, 0, stream>>>(Wg1, Wg1hi, Wg1lo, 512*512/4);
    csplit_k<<<(512*512/4 + 255)/256, 256, 0, stream>>>(Wg2, Wg2hi, Wg2lo, 512*512/4);

    // -------- CSR build -----------------------------------------------------
    hipMemsetAsync(deg, 0, NN_ * 8, stream);            // deg + cursor
    count_deg_k<<<EG, 256, 0, stream>>>(eAB, eBA, deg);
    scan_k<<<1, 256, 0, stream>>>(deg, rowst);
    fill_csr_k<<<EG, 256, 0, stream>>>(eAB, eBA, rowst, cursor, csr);

    // -------- local branch --------------------------------------------------
    mgemm_in_k<true><<<dim3(4, 64), 256, 0, stream>>>(
        xbA, xbB, WbinA, WbinB, b_inA, b_inB, qb, kb);          // l0 split
    mgemm3_k<<<dim3(4, 64), 256, 0, stream>>>(qb, kb, Wg1hi, Wg1lo,
                                              bufB, hb, 512, 512, 512, 512);
    node_dots_k<<<NN_/4, 256, 0, stream>>>(bufB, a_src1, a_dst1, as_, ad_);
    hipMemsetAsync(mkey, 0, NN_ * 8, stream);           // mkey + denom
    edge_pass1_k<<<EG, 256, 0, stream>>>(eAB, eBA, as_, ad_, evals, mkey);
    edge_pass2_k<<<EG, 256, 0, stream>>>(eAB, eBA, mkey, evals, denom);
    gat_agg_k<true><<<NN_/4, 256, 0, stream>>>(eAB, eBA, rowst, csr, evals, denom,
                                               hb, bg1, nullptr, qb, kb);
    mgemm3_k<<<dim3(4, 64), 256, 0, stream>>>(qb, kb, Wg2hi, Wg2lo,
                                              bufB, hb, 512, 512, 512, 512);
    node_dots_k<<<NN_/4, 256, 0, stream>>>(bufB, a_src2, a_dst2, as_, ad_);
    hipMemsetAsync(mkey, 0, NN_ * 8, stream);
    edge_pass1_k<<<EG, 256, 0, stream>>>(eAB, eBA, as_, ad_, evals, mkey);
    edge_pass2_k<<<EG, 256, 0, stream>>>(eAB, eBA, mkey, evals, denom);
    gat_agg_k<false><<<NN_/4, 256, 0, stream>>>(eAB, eBA, rowst, csr, evals, denom,
                                                hb, bg2, bufA, nullptr, nullptr);
    store_half_k<<<(NN_*512)/256, 256, 0, stream>>>(bufA, out, 0);

    // -------- global branch -------------------------------------------------
    mgemm_in_k<false><<<dim3(4, 64), 256, 0, stream>>>(
        xbA, xbB, Wbin2A, Wbin2B, b_in2A, b_in2B, gb, nullptr); // g bf16 only
    mgemm_qkv_k<<<dim3(12, 64), 256, 0, stream>>>(gb, Wbqkv, bqkv, qb, kb, vb);
    trT_k<<<dim3(8, 128), 256, 0, stream>>>(vb, vT);
    for (int c0 = 0; c0 < 8192; c0 += R) {
        mgemm_k<128,128,false,unsigned short><<<dim3(64, R/128), 256, 0, stream>>>(
            qb + (size_t)c0 * 512, kb, nullptr, Sb, 512, 512, 512, 8192);
        softmax_bf16_k<<<R, 256, 0, stream>>>(Sb, scale);
        mgemm_pv_k<<<dim3(4, R/128, SEGS), 256, 0, stream>>>(
            Sb, vT, pv, KSEG, (size_t)R * 512);
        radd_k<<<(R*512/4 + 255)/256, 256, 0, stream>>>(
            pv, ab + (size_t)c0 * 512, R*512/4, SEGS, (size_t)R*512/4);
    }
    mgemm_k<128,128,true,float><<<dim3(4, 64), 256, 0, stream>>>(
        ab, Wbo, bo, bufC, 512, 512, 512, 512);
    store_half_k<<<(NN_*512)/256, 256, 0, stream>>>(bufC, out, 512);
}

// Round 10
// 685.529 us; speedup vs baseline: 10.2085x; 1.1107x over previous
//
#include <hip/hip_runtime.h>
#include <hip/hip_bf16.h>

#define NA_ 4096
#define NB_ 4096
#define NN_ 8192            // total nodes
#define EE_ 131072          // edges per direction
#define NE_ (2*EE_ + NN_)   // homogeneous edges incl. self loops = 270336
#define HH_ 512
#define NEG_SLOPE_ 0.2f

typedef __attribute__((ext_vector_type(4))) float f32x4;
typedef __attribute__((ext_vector_type(8))) short s16x8;

__device__ inline unsigned short f2bf(float v) {
    __hip_bfloat16 h = __float2bfloat16(v);
    return __builtin_bit_cast(unsigned short, h);
}
__device__ inline float bf2f(unsigned short u) {
    return __uint_as_float(((unsigned)u) << 16);
}

// ---------------- float-order <-> unsigned-order mapping for atomic max ----
__device__ inline unsigned fkey(float f) {
    unsigned b = __float_as_uint(f);
    return (b & 0x80000000u) ? ~b : (b | 0x80000000u);
}
__device__ inline float finv(unsigned k) {
    return (k & 0x80000000u) ? __uint_as_float(k & 0x7fffffffu)
                             : __uint_as_float(~k);
}

// ---------------- homogeneous edge id -> (src, dst) ------------------------
__device__ inline void edge_sd(int i, const int* __restrict__ eAB,
                               const int* __restrict__ eBA, int& s, int& d) {
    if (i < EE_)            { s = eAB[i];            d = eAB[EE_ + i] + NA_; }
    else if (i < 2 * EE_)   { int j = i - EE_; s = eBA[j] + NA_; d = eBA[EE_ + j]; }
    else                    { s = i - 2 * EE_;       d = s; }
}

// ---------------- f32 -> bf16 cast (vectorized) ----------------------------
__global__ __launch_bounds__(256) void cvtb_k(const float* __restrict__ s,
                                              unsigned short* __restrict__ d, int n4) {
    int i = blockIdx.x * 256 + threadIdx.x;
    if (i >= n4) return;
    float4 v = ((const float4*)s)[i];
    ushort4 o;
    o.x = f2bf(v.x); o.y = f2bf(v.y); o.z = f2bf(v.z); o.w = f2bf(v.w);
    ((ushort4*)d)[i] = o;
}

// ---------------- f32 -> (bf16 hi, bf16 lo) split cast ---------------------
__global__ __launch_bounds__(256) void csplit_k(const float* __restrict__ s,
                                                unsigned short* __restrict__ hi,
                                                unsigned short* __restrict__ lo, int n4) {
    int i = blockIdx.x * 256 + threadIdx.x;
    if (i >= n4) return;
    float4 v = ((const float4*)s)[i];
    ushort4 h, l;
    h.x = f2bf(v.x); l.x = f2bf(v.x - bf2f(h.x));
    h.y = f2bf(v.y); l.y = f2bf(v.y - bf2f(h.y));
    h.z = f2bf(v.z); l.z = f2bf(v.z - bf2f(h.z));
    h.w = f2bf(v.w); l.w = f2bf(v.w - bf2f(h.w));
    ((ushort4*)hi)[i] = h;
    ((ushort4*)lo)[i] = l;
}

// ---------------- MFMA bf16 GEMM: C[M,N] = A @ B^T (+bias) -----------------
template<int BM, int BN, bool BIAS, typename OutT>
__global__ __launch_bounds__(256) void mgemm_k(
    const unsigned short* __restrict__ A, const unsigned short* __restrict__ B,
    const float* __restrict__ bias, OutT* __restrict__ C,
    int K, int lda, int ldb, int ldc)
{
    constexpr int BK = 32;
    constexpr int WM = BM / 2, WN = BN / 2;
    constexpr int AM = WM / 16, AN = WN / 16;
    constexpr int AISS = BM * 4 / 256, BISS = BN * 4 / 256;
    __shared__ unsigned short sA[BM * BK];
    __shared__ unsigned short sB[BN * BK];
    const int t = threadIdx.x, lane = t & 63, w = t >> 6;
    const int wr = w >> 1, wc = w & 1;
    const int fr = lane & 15, fq = lane >> 4;
    const int bm = blockIdx.y * BM, bn = blockIdx.x * BN;

    f32x4 acc[AM][AN];
    #pragma unroll
    for (int m = 0; m < AM; m++)
        #pragma unroll
        for (int n = 0; n < AN; n++)
            #pragma unroll
            for (int r = 0; r < 4; r++) acc[m][n][r] = 0.f;

    for (int k0 = 0; k0 < K; k0 += BK) {
        __syncthreads();
        #pragma unroll
        for (int i = 0; i < AISS; i++) {
            int slot = i * 256 + t;
            __builtin_amdgcn_global_load_lds(
                (const __attribute__((address_space(1))) unsigned int*)
                    (A + (size_t)(bm + (slot >> 2)) * lda + k0 + (slot & 3) * 8),
                (__attribute__((address_space(3))) unsigned int*)
                    (sA + (i * 256 + w * 64) * 8), 16, 0, 0);
        }
        #pragma unroll
        for (int i = 0; i < BISS; i++) {
            int slot = i * 256 + t;
            __builtin_amdgcn_global_load_lds(
                (const __attribute__((address_space(1))) unsigned int*)
                    (B + (size_t)(bn + (slot >> 2)) * ldb + k0 + (slot & 3) * 8),
                (__attribute__((address_space(3))) unsigned int*)
                    (sB + (i * 256 + w * 64) * 8), 16, 0, 0);
        }
        __syncthreads();
        s16x8 a[AM], b[AN];
        #pragma unroll
        for (int m = 0; m < AM; m++)
            a[m] = *(const s16x8*)&sA[(wr * WM + m * 16 + fr) * BK + fq * 8];
        #pragma unroll
        for (int n = 0; n < AN; n++)
            b[n] = *(const s16x8*)&sB[(wc * WN + n * 16 + fr) * BK + fq * 8];
        #pragma unroll
        for (int m = 0; m < AM; m++)
            #pragma unroll
            for (int n = 0; n < AN; n++)
                acc[m][n] = __builtin_amdgcn_mfma_f32_16x16x32_bf16(a[m], b[n], acc[m][n], 0, 0, 0);
    }

    // C/D layout: col = lane&15, row = (lane>>4)*4 + reg
    #pragma unroll
    for (int m = 0; m < AM; m++) {
        const int row = bm + wr * WM + m * 16 + fq * 4;
        #pragma unroll
        for (int n = 0; n < AN; n++) {
            const int col = bn + wc * WN + n * 16 + fr;
            const float bv = BIAS ? bias[col] : 0.f;
            #pragma unroll
            for (int r = 0; r < 4; r++) {
                float v = acc[m][n][r] + bv;
                if constexpr (sizeof(OutT) == 2)
                    C[(size_t)(row + r) * ldc + col] = (OutT)f2bf(v);
                else
                    C[(size_t)(row + r) * ldc + col] = v;
            }
        }
    }
}

// ---------------- merged per-type input linear (A rows 0..4095, B rows 4096+)
template<bool SPLIT>
__global__ __launch_bounds__(256) void mgemm_in_k(
    const unsigned short* __restrict__ xA, const unsigned short* __restrict__ xB,
    const unsigned short* __restrict__ WA, const unsigned short* __restrict__ WB,
    const float* __restrict__ biasA, const float* __restrict__ biasB,
    unsigned short* __restrict__ o1, unsigned short* __restrict__ o2)
{
    constexpr int BK = 32;
    __shared__ unsigned short sA[128 * BK];
    __shared__ unsigned short sB[128 * BK];
    const int t = threadIdx.x, lane = t & 63, w = t >> 6;
    const int wr = w >> 1, wc = w & 1;
    const int fr = lane & 15, fq = lane >> 4;
    const int bm = blockIdx.y * 128, bn = blockIdx.x * 128;
    const bool isB = bm >= NA_;
    const unsigned short* A = isB ? xB : xA;
    const unsigned short* W = isB ? WB : WA;
    const float* bias = isB ? biasB : biasA;
    const int bml = bm - (isB ? NA_ : 0);

    f32x4 acc[4][4];
    #pragma unroll
    for (int m = 0; m < 4; m++)
        #pragma unroll
        for (int n = 0; n < 4; n++)
            #pragma unroll
            for (int r = 0; r < 4; r++) acc[m][n][r] = 0.f;

    for (int k0 = 0; k0 < 256; k0 += BK) {
        __syncthreads();
        #pragma unroll
        for (int i = 0; i < 2; i++) {
            int slot = i * 256 + t;
            __builtin_amdgcn_global_load_lds(
                (const __attribute__((address_space(1))) unsigned int*)
                    (A + (size_t)(bml + (slot >> 2)) * 256 + k0 + (slot & 3) * 8),
                (__attribute__((address_space(3))) unsigned int*)
                    (sA + (i * 256 + w * 64) * 8), 16, 0, 0);
            __builtin_amdgcn_global_load_lds(
                (const __attribute__((address_space(1))) unsigned int*)
                    (W + (size_t)(bn + (slot >> 2)) * 256 + k0 + (slot & 3) * 8),
                (__attribute__((address_space(3))) unsigned int*)
                    (sB + (i * 256 + w * 64) * 8), 16, 0, 0);
        }
        __syncthreads();
        s16x8 a[4], b[4];
        #pragma unroll
        for (int m = 0; m < 4; m++)
            a[m] = *(const s16x8*)&sA[(wr * 64 + m * 16 + fr) * BK + fq * 8];
        #pragma unroll
        for (int n = 0; n < 4; n++)
            b[n] = *(const s16x8*)&sB[(wc * 64 + n * 16 + fr) * BK + fq * 8];
        #pragma unroll
        for (int m = 0; m < 4; m++)
            #pragma unroll
            for (int n = 0; n < 4; n++)
                acc[m][n] = __builtin_amdgcn_mfma_f32_16x16x32_bf16(a[m], b[n], acc[m][n], 0, 0, 0);
    }

    #pragma unroll
    for (int m = 0; m < 4; m++) {
        const int row = bm + wr * 64 + m * 16 + fq * 4;
        #pragma unroll
        for (int n = 0; n < 4; n++) {
            const int col = bn + wc * 64 + n * 16 + fr;
            const float bv = bias[col];
            #pragma unroll
            for (int r = 0; r < 4; r++) {
                float v = acc[m][n][r] + bv;
                unsigned short hi = f2bf(v);
                o1[(size_t)(row + r) * 512 + col] = hi;
                if (SPLIT)
                    o2[(size_t)(row + r) * 512 + col] = f2bf(v - bf2f(hi));
            }
        }
    }
}

// ---------------- split-precision MFMA GEMM (~f32 accuracy) ----------------
__global__ __launch_bounds__(256) void mgemm3_k(
    const unsigned short* __restrict__ Ahi, const unsigned short* __restrict__ Alo,
    const unsigned short* __restrict__ Bhi, const unsigned short* __restrict__ Blo,
    float* __restrict__ C, unsigned short* __restrict__ Cb,
    int K, int lda, int ldb, int ldc)
{
    constexpr int BM = 128, BN = 128, BK = 32;
    __shared__ unsigned short sAh[BM * BK], sAl[BM * BK];
    __shared__ unsigned short sBh[BN * BK], sBl[BN * BK];
    const int t = threadIdx.x, lane = t & 63, w = t >> 6;
    const int wr = w >> 1, wc = w & 1;
    const int fr = lane & 15, fq = lane >> 4;
    const int bm = blockIdx.y * BM, bn = blockIdx.x * BN;

    f32x4 acc[4][4];
    #pragma unroll
    for (int m = 0; m < 4; m++)
        #pragma unroll
        for (int n = 0; n < 4; n++)
            #pragma unroll
            for (int r = 0; r < 4; r++) acc[m][n][r] = 0.f;

    for (int k0 = 0; k0 < K; k0 += BK) {
        __syncthreads();
        #pragma unroll
        for (int i = 0; i < 2; i++) {
            int slot = i * 256 + t;
            size_t ga = (size_t)(bm + (slot >> 2)) * lda + k0 + (slot & 3) * 8;
            size_t gb = (size_t)(bn + (slot >> 2)) * ldb + k0 + (slot & 3) * 8;
            unsigned loff = (unsigned)(i * 256 + w * 64) * 8;
            __builtin_amdgcn_global_load_lds(
                (const __attribute__((address_space(1))) unsigned int*)(Ahi + ga),
                (__attribute__((address_space(3))) unsigned int*)(sAh + loff), 16, 0, 0);
            __builtin_amdgcn_global_load_lds(
                (const __attribute__((address_space(1))) unsigned int*)(Alo + ga),
                (__attribute__((address_space(3))) unsigned int*)(sAl + loff), 16, 0, 0);
            __builtin_amdgcn_global_load_lds(
                (const __attribute__((address_space(1))) unsigned int*)(Bhi + gb),
                (__attribute__((address_space(3))) unsigned int*)(sBh + loff), 16, 0, 0);
            __builtin_amdgcn_global_load_lds(
                (const __attribute__((address_space(1))) unsigned int*)(Blo + gb),
                (__attribute__((address_space(3))) unsigned int*)(sBl + loff), 16, 0, 0);
        }
        __syncthreads();
        s16x8 ah[4], al[4], bh[4], bl[4];
        #pragma unroll
        for (int m = 0; m < 4; m++) {
            int o = (wr * 64 + m * 16 + fr) * BK + fq * 8;
            ah[m] = *(const s16x8*)&sAh[o];
            al[m] = *(const s16x8*)&sAl[o];
        }
        #pragma unroll
        for (int n = 0; n < 4; n++) {
            int o = (wc * 64 + n * 16 + fr) * BK + fq * 8;
            bh[n] = *(const s16x8*)&sBh[o];
            bl[n] = *(const s16x8*)&sBl[o];
        }
        #pragma unroll
        for (int m = 0; m < 4; m++)
            #pragma unroll
            for (int n = 0; n < 4; n++) {
                acc[m][n] = __builtin_amdgcn_mfma_f32_16x16x32_bf16(ah[m], bh[n], acc[m][n], 0, 0, 0);
                acc[m][n] = __builtin_amdgcn_mfma_f32_16x16x32_bf16(ah[m], bl[n], acc[m][n], 0, 0, 0);
                acc[m][n] = __builtin_amdgcn_mfma_f32_16x16x32_bf16(al[m], bh[n], acc[m][n], 0, 0, 0);
            }
    }

    #pragma unroll
    for (int m = 0; m < 4; m++) {
        const int row = bm + wr * 64 + m * 16 + fq * 4;
        #pragma unroll
        for (int n = 0; n < 4; n++) {
            const int col = bn + wc * 64 + n * 16 + fr;
            #pragma unroll
            for (int r = 0; r < 4; r++) {
                float v = acc[m][n][r];
                C[(size_t)(row + r) * ldc + col]  = v;
                Cb[(size_t)(row + r) * 512 + col] = f2bf(v);
            }
        }
    }
}

// ---------------- PV split-K MFMA GEMM (bf16 partials, XCD swizzle) --------
// grid (4, 16, SEGS); swizzled so the 4 N-blocks sharing a P-panel map to the
// same XCD (L2 locality on A). Partials: seg z -> C + z*segstride, bf16.
__global__ __launch_bounds__(256) void mgemm_pv_k(
    const unsigned short* __restrict__ A, const unsigned short* __restrict__ B,
    unsigned short* __restrict__ C, int kseg, size_t segstride)
{
    constexpr int BM = 128, BN = 128, BK = 32;
    __shared__ unsigned short sA[BM * BK];
    __shared__ unsigned short sB[BN * BK];
    const int t = threadIdx.x, lane = t & 63, w = t >> 6;
    const int wr = w >> 1, wc = w & 1;
    const int fr = lane & 15, fq = lane >> 4;
    // XCD swizzle: L = x + 4y + 64z ; xs slowest so same-(ys,zs) blocks share
    // XCD class (ys mod 8): A-panel fetched once per XCD instead of 4x.
    const int L  = blockIdx.x + (blockIdx.y << 2) + (blockIdx.z << 6);
    const int xs = L >> 7;
    const int ys = (L & 127) & 15;
    const int zs = (L & 127) >> 4;
    const int bm = ys * BM, bn = xs * BN;
    const int kofs = zs * kseg;

    f32x4 acc[4][4];
    #pragma unroll
    for (int m = 0; m < 4; m++)
        #pragma unroll
        for (int n = 0; n < 4; n++)
            #pragma unroll
            for (int r = 0; r < 4; r++) acc[m][n][r] = 0.f;

    for (int k0 = 0; k0 < kseg; k0 += BK) {
        __syncthreads();
        #pragma unroll
        for (int i = 0; i < 2; i++) {
            int slot = i * 256 + t;
            __builtin_amdgcn_global_load_lds(
                (const __attribute__((address_space(1))) unsigned int*)
                    (A + (size_t)(bm + (slot >> 2)) * 8192 + kofs + k0 + (slot & 3) * 8),
                (__attribute__((address_space(3))) unsigned int*)
                    (sA + (i * 256 + w * 64) * 8), 16, 0, 0);
            __builtin_amdgcn_global_load_lds(
                (const __attribute__((address_space(1))) unsigned int*)
                    (B + (size_t)(bn + (slot >> 2)) * 8192 + kofs + k0 + (slot & 3) * 8),
                (__attribute__((address_space(3))) unsigned int*)
                    (sB + (i * 256 + w * 64) * 8), 16, 0, 0);
        }
        __syncthreads();
        s16x8 a[4], b[4];
        #pragma unroll
        for (int m = 0; m < 4; m++)
            a[m] = *(const s16x8*)&sA[(wr * 64 + m * 16 + fr) * BK + fq * 8];
        #pragma unroll
        for (int n = 0; n < 4; n++)
            b[n] = *(const s16x8*)&sB[(wc * 64 + n * 16 + fr) * BK + fq * 8];
        #pragma unroll
        for (int m = 0; m < 4; m++)
            #pragma unroll
            for (int n = 0; n < 4; n++)
                acc[m][n] = __builtin_amdgcn_mfma_f32_16x16x32_bf16(a[m], b[n], acc[m][n], 0, 0, 0);
    }

    unsigned short* Cz = C + (size_t)zs * segstride;
    #pragma unroll
    for (int m = 0; m < 4; m++) {
        const int row = bm + wr * 64 + m * 16 + fq * 4;
        #pragma unroll
        for (int n = 0; n < 4; n++) {
            const int col = bn + wc * 64 + n * 16 + fr;
            #pragma unroll
            for (int r = 0; r < 4; r++)
                Cz[(size_t)(row + r) * 512 + col] = f2bf(acc[m][n][r]);
        }
    }
}

// ---------------- reduce bf16 split-K partials -> bf16 ----------------------
__global__ __launch_bounds__(256) void radd_k(const unsigned short* __restrict__ src,
                                              unsigned short* __restrict__ dst,
                                              int n8, int segs, size_t stride8) {
    int i = blockIdx.x * 256 + threadIdx.x;
    if (i >= n8) return;
    float acc[8] = {0,0,0,0,0,0,0,0};
    for (int s = 0; s < segs; s++) {
        s16x8 v = ((const s16x8*)src)[i + s * stride8];
        #pragma unroll
        for (int j = 0; j < 8; j++) acc[j] += bf2f((unsigned short)v[j]);
    }
    s16x8 o;
    #pragma unroll
    for (int j = 0; j < 8; j++) o[j] = (short)f2bf(acc[j]);
    ((s16x8*)dst)[i] = o;
}

// ---------------- qkv MFMA GEMM with split epilogue (scale folded into q) ---
__global__ __launch_bounds__(256) void mgemm_qkv_k(
    const unsigned short* __restrict__ A, const unsigned short* __restrict__ B,
    const float* __restrict__ bias, float scale,
    unsigned short* __restrict__ qb, unsigned short* __restrict__ kb,
    unsigned short* __restrict__ vb)
{
    constexpr int BM = 128, BN = 128, BK = 32;
    __shared__ unsigned short sA[BM * BK];
    __shared__ unsigned short sB[BN * BK];
    const int t = threadIdx.x, lane = t & 63, w = t >> 6;
    const int wr = w >> 1, wc = w & 1;
    const int fr = lane & 15, fq = lane >> 4;
    const int bm = blockIdx.y * BM, bn = blockIdx.x * BN;

    f32x4 acc[4][4];
    #pragma unroll
    for (int m = 0; m < 4; m++)
        #pragma unroll
        for (int n = 0; n < 4; n++)
            #pragma unroll
            for (int r = 0; r < 4; r++) acc[m][n][r] = 0.f;

    for (int k0 = 0; k0 < 512; k0 += BK) {
        __syncthreads();
        #pragma unroll
        for (int i = 0; i < 2; i++) {
            int slot = i * 256 + t;
            __builtin_amdgcn_global_load_lds(
                (const __attribute__((address_space(1))) unsigned int*)
                    (A + (size_t)(bm + (slot >> 2)) * 512 + k0 + (slot & 3) * 8),
                (__attribute__((address_space(3))) unsigned int*)
                    (sA + (i * 256 + w * 64) * 8), 16, 0, 0);
            __builtin_amdgcn_global_load_lds(
                (const __attribute__((address_space(1))) unsigned int*)
                    (B + (size_t)(bn + (slot >> 2)) * 512 + k0 + (slot & 3) * 8),
                (__attribute__((address_space(3))) unsigned int*)
                    (sB + (i * 256 + w * 64) * 8), 16, 0, 0);
        }
        __syncthreads();
        s16x8 a[4], b[4];
        #pragma unroll
        for (int m = 0; m < 4; m++)
            a[m] = *(const s16x8*)&sA[(wr * 64 + m * 16 + fr) * BK + fq * 8];
        #pragma unroll
        for (int n = 0; n < 4; n++)
            b[n] = *(const s16x8*)&sB[(wc * 64 + n * 16 + fr) * BK + fq * 8];
        #pragma unroll
        for (int m = 0; m < 4; m++)
            #pragma unroll
            for (int n = 0; n < 4; n++)
                acc[m][n] = __builtin_amdgcn_mfma_f32_16x16x32_bf16(a[m], b[n], acc[m][n], 0, 0, 0);
    }

    #pragma unroll
    for (int m = 0; m < 4; m++) {
        const int row = bm + wr * 64 + m * 16 + fq * 4;
        #pragma unroll
        for (int n = 0; n < 4; n++) {
            const int col = bn + wc * 64 + n * 16 + fr;
            const float bv = bias[col];
            #pragma unroll
            for (int r = 0; r < 4; r++) {
                float v = acc[m][n][r] + bv;
                if (col < 512)
                    qb[(size_t)(row + r) * 512 + col] = f2bf(v * scale);
                else if (col < 1024)
                    kb[(size_t)(row + r) * 512 + (col - 512)] = f2bf(v);
                else
                    vb[(size_t)(row + r) * 512 + (col - 1024)] = f2bf(v);
            }
        }
    }
}

// ---------------- bf16 transpose: vb[8192][512] -> vT[512][8192] ------------
__global__ __launch_bounds__(256) void trT_k(const unsigned short* __restrict__ vb,
                                             unsigned short* __restrict__ vT) {
    __shared__ unsigned short s[64][65];
    const int t = threadIdx.x;
    const int rowo = blockIdx.y * 64;
    const int colo = blockIdx.x * 64;
    {
        int r = t >> 2, cg = (t & 3) * 16;
        const s16x8* src = (const s16x8*)(vb + (size_t)(rowo + r) * 512 + colo + cg);
        s16x8 u0 = src[0], u1 = src[1];
        #pragma unroll
        for (int j = 0; j < 8; j++) {
            s[r][cg + j]     = (unsigned short)u0[j];
            s[r][cg + 8 + j] = (unsigned short)u1[j];
        }
    }
    __syncthreads();
    {
        int c = t >> 2, rg = (t & 3) * 16;
        s16x8 o0, o1;
        #pragma unroll
        for (int j = 0; j < 8; j++) {
            o0[j] = (short)s[rg + j][c];
            o1[j] = (short)s[rg + 8 + j][c];
        }
        s16x8* dst = (s16x8*)(vT + (size_t)(colo + c) * 8192 + rowo + rg);
        dst[0] = o0; dst[1] = o1;
    }
}

// ---------------- per-node attention dots (wave per node) -------------------
__global__ __launch_bounds__(256) void node_dots_k(
    const float* __restrict__ h, const float* __restrict__ a_src,
    const float* __restrict__ a_dst, float* __restrict__ as_, float* __restrict__ ad_)
{
    int wid  = (blockIdx.x * 256 + threadIdx.x) >> 6;
    int lane = threadIdx.x & 63;
    if (wid >= NN_) return;
    const float* hr = h + (size_t)wid * HH_;
    float s1 = 0.f, s2 = 0.f;
    #pragma unroll
    for (int j = 0; j < 8; j++) {
        float v = hr[lane + j*64];
        s1 = fmaf(v, a_src[lane + j*64], s1);
        s2 = fmaf(v, a_dst[lane + j*64], s2);
    }
    #pragma unroll
    for (int off = 32; off; off >>= 1) {
        s1 += __shfl_down(s1, off);
        s2 += __shfl_down(s2, off);
    }
    if (lane == 0) { as_[wid] = s1; ad_[wid] = s2; }
}

// ---------------- CSR build ------------------------------------------------
__global__ void count_deg_k(const int* eAB, const int* eBA, int* deg) {
    int i = blockIdx.x * 256 + threadIdx.x;
    if (i >= NE_) return;
    int s, d; edge_sd(i, eAB, eBA, s, d);
    atomicAdd(&deg[d], 1);
}

__global__ __launch_bounds__(256) void scan_k(const int* __restrict__ deg, int* rowstart) {
    __shared__ int part[256];
    int t = threadIdx.x;
    int base = t * 32;
    int loc[32]; int s = 0;
    #pragma unroll
    for (int j = 0; j < 32; j++) { loc[j] = s; s += deg[base + j]; }
    part[t] = s;
    __syncthreads();
    if (t == 0) {
        int a = 0;
        for (int i = 0; i < 256; i++) { int v = part[i]; part[i] = a; a += v; }
        rowstart[NN_] = a;
    }
    __syncthreads();
    int off = part[t];
    #pragma unroll
    for (int j = 0; j < 32; j++) rowstart[base + j] = off + loc[j];
}

__global__ void fill_csr_k(const int* eAB, const int* eBA,
                           const int* __restrict__ rowstart, int* cursor, int* csr) {
    int i = blockIdx.x * 256 + threadIdx.x;
    if (i >= NE_) return;
    int s, d; edge_sd(i, eAB, eBA, s, d);
    int pos = atomicAdd(&cursor[d], 1);
    csr[rowstart[d] + pos] = i;
}

// ---------------- GAT edge passes ------------------------------------------
__global__ void edge_pass1_k(const int* eAB, const int* eBA,
                             const float* __restrict__ as_, const float* __restrict__ ad_,
                             float* evals, unsigned* mkey) {
    int i = blockIdx.x * 256 + threadIdx.x;
    if (i >= NE_) return;
    int s, d; edge_sd(i, eAB, eBA, s, d);
    float e = as_[s] + ad_[d];
    e = (e >= 0.f) ? e : NEG_SLOPE_ * e;
    evals[i] = e;
    atomicMax(&mkey[d], fkey(e));
}

__global__ void edge_pass2_k(const int* eAB, const int* eBA,
                             const unsigned* __restrict__ mkey,
                             float* evals, float* denom) {
    int i = blockIdx.x * 256 + threadIdx.x;
    if (i >= NE_) return;
    int s, d; edge_sd(i, eAB, eBA, s, d);
    float m = finv(mkey[d]);
    float ex = expf(evals[i] - m);
    evals[i] = ex;
    atomicAdd(&denom[d], ex);
}

// ---------------- GAT aggregation (CSR gather, bf16 h, wave per node) -------
template<bool SPLIT>
__global__ __launch_bounds__(256) void gat_agg_k(
    const int* eAB, const int* eBA,
    const int* __restrict__ rowstart, const int* __restrict__ csr,
    const float* __restrict__ evals, const float* __restrict__ denom,
    const unsigned short* __restrict__ hb, const float* __restrict__ bias,
    float* __restrict__ outF, unsigned short* __restrict__ outHi,
    unsigned short* __restrict__ outLo)
{
    int wid  = (blockIdx.x * 256 + threadIdx.x) >> 6;
    int lane = threadIdx.x & 63;
    if (wid >= NN_) return;
    float acc[8] = {0.f,0.f,0.f,0.f,0.f,0.f,0.f,0.f};
    int beg = rowstart[wid], end = rowstart[wid + 1];
    float rden = 1.0f / denom[wid];
    for (int p = beg; p < end; p++) {
        int eid = csr[p];
        int s, d; edge_sd(eid, eAB, eBA, s, d);
        float alpha = evals[eid] * rden;
        s16x8 hv = *(const s16x8*)(hb + (size_t)s * HH_ + lane * 8);
        #pragma unroll
        for (int j = 0; j < 8; j++)
            acc[j] = fmaf(alpha, bf2f((unsigned short)hv[j]), acc[j]);
    }
    #pragma unroll
    for (int j = 0; j < 8; j++) acc[j] += bias[lane * 8 + j];
    if (SPLIT) {
        s16x8 hi, lo;
        #pragma unroll
        for (int j = 0; j < 8; j++) {
            unsigned short h = f2bf(acc[j]);
            hi[j] = (short)h;
            lo[j] = (short)f2bf(acc[j] - bf2f(h));
        }
        *(s16x8*)(outHi + (size_t)wid * HH_ + lane * 8) = hi;
        *(s16x8*)(outLo + (size_t)wid * HH_ + lane * 8) = lo;
    } else {
        float* o = outF + (size_t)wid * HH_ + lane * 8;
        *(float4*)(o)     = make_float4(acc[0], acc[1], acc[2], acc[3]);
        *(float4*)(o + 4) = make_float4(acc[4], acc[5], acc[6], acc[7]);
    }
}

// ---------------- bf16 row softmax over 8192 columns (in place; pre-scaled) -
__global__ __launch_bounds__(256) void softmax_bf16_k(unsigned short* __restrict__ S) {
    __shared__ float red[8];
    const int row = blockIdx.x, t = threadIdx.x;
    uint4* rp = (uint4*)(S + (size_t)row * 8192);
    float v[32];
    uint4 u[4];
    float mx = -3.0e38f;
    #pragma unroll
    for (int i = 0; i < 4; i++) {
        u[i] = rp[t + i * 256];
        const unsigned* uw = (const unsigned*)&u[i];
        #pragma unroll
        for (int j = 0; j < 4; j++) {
            float lo = __uint_as_float(uw[j] << 16);
            float hi = __uint_as_float(uw[j] & 0xffff0000u);
            v[i*8 + 2*j]     = lo;
            v[i*8 + 2*j + 1] = hi;
            mx = fmaxf(mx, fmaxf(lo, hi));
        }
    }
    #pragma unroll
    for (int o = 32; o; o >>= 1) mx = fmaxf(mx, __shfl_down(mx, o));
    if ((t & 63) == 0) red[t >> 6] = mx;
    __syncthreads();
    mx = fmaxf(fmaxf(red[0], red[1]), fmaxf(red[2], red[3]));
    float sum = 0.f;
    #pragma unroll
    for (int i = 0; i < 32; i++) { float p = expf(v[i] - mx); v[i] = p; sum += p; }
    #pragma unroll
    for (int o = 32; o; o >>= 1) sum += __shfl_down(sum, o);
    if ((t & 63) == 0) red[4 + (t >> 6)] = sum;
    __syncthreads();
    const float rs = 1.0f / (red[4] + red[5] + red[6] + red[7]);
    #pragma unroll
    for (int i = 0; i < 4; i++) {
        unsigned* uw = (unsigned*)&u[i];
        #pragma unroll
        for (int j = 0; j < 4; j++)
            uw[j] = (unsigned)f2bf(v[i*8 + 2*j] * rs)
                  | ((unsigned)f2bf(v[i*8 + 2*j + 1] * rs) << 16);
        rp[t + i * 256] = u[i];
    }
}

// ---------------- flush one 512-col half into the f32 output ----------------
__global__ __launch_bounds__(256) void store_half_k(
    const float* __restrict__ src, float* __restrict__ out, int col0)
{
    int i = blockIdx.x * 256 + threadIdx.x;
    if (i >= NN_ * 512) return;
    int node = i >> 9, c = i & 511;
    out[(size_t)node * 1024 + col0 + c] = src[i];
}

// ===========================================================================
extern "C" void kernel_launch(void* const* d_in, const int* in_sizes, int n_in,
                              void* d_out, int out_size, void* d_ws, size_t ws_size,
                              hipStream_t stream)
{
    const float* x_A    = (const float*)d_in[0];
    const float* x_B    = (const float*)d_in[1];
    const int*   eAB    = (const int*)d_in[2];
    const int*   eBA    = (const int*)d_in[3];
    const float* W_inA  = (const float*)d_in[4];  const float* b_inA  = (const float*)d_in[5];
    const float* W_inB  = (const float*)d_in[6];  const float* b_inB  = (const float*)d_in[7];
    const float* W_in2A = (const float*)d_in[8];  const float* b_in2A = (const float*)d_in[9];
    const float* W_in2B = (const float*)d_in[10]; const float* b_in2B = (const float*)d_in[11];
    const float* Wg1    = (const float*)d_in[12]; const float* a_src1 = (const float*)d_in[13];
    const float* a_dst1 = (const float*)d_in[14]; const float* bg1    = (const float*)d_in[15];
    const float* Wg2    = (const float*)d_in[16]; const float* a_src2 = (const float*)d_in[17];
    const float* a_dst2 = (const float*)d_in[18]; const float* bg2    = (const float*)d_in[19];
    const float* Wqkv   = (const float*)d_in[20]; const float* bqkv   = (const float*)d_in[21];
    const float* Wo     = (const float*)d_in[22]; const float* bo     = (const float*)d_in[23];

    float* out = (float*)d_out;

    char* base = (char*)d_ws;
    size_t off = 0;
    auto alloc = [&](size_t nb) -> char* {
        char* p = base + off;
        off = (off + nb + 255) & ~(size_t)255;
        return p;
    };

    // bufA and bufB MUST be adjacent: Sb (32MB) spans both during attention.
    float*          bufA  = (float*)alloc((size_t)NN_ * 512 * 4);
    float*          bufB  = (float*)alloc((size_t)NN_ * 512 * 4);
    float*          bufC  = (float*)alloc((size_t)NN_ * 512 * 4);
    float*          as_   = (float*)alloc(NN_ * 4);
    float*          ad_   = (float*)alloc(NN_ * 4);
    unsigned*       mkey  = (unsigned*)alloc(NN_ * 4);
    float*          denom = (float*)alloc(NN_ * 4);
    int*            deg   = (int*)alloc(NN_ * 4);
    int*            cursor= (int*)alloc(NN_ * 4);
    int*            rowst = (int*)alloc((NN_ + 1) * 4);
    float*          evals = (float*)alloc((size_t)NE_ * 4);
    int*            csr   = (int*)alloc((size_t)NE_ * 4);
    unsigned short* xbA   = (unsigned short*)alloc((size_t)NA_ * 256 * 2);
    unsigned short* xbB   = (unsigned short*)alloc((size_t)NB_ * 256 * 2);
    unsigned short* WbinA = (unsigned short*)alloc((size_t)512 * 256 * 2);
    unsigned short* WbinB = (unsigned short*)alloc((size_t)512 * 256 * 2);
    unsigned short* Wbin2A= (unsigned short*)alloc((size_t)512 * 256 * 2);
    unsigned short* Wbin2B= (unsigned short*)alloc((size_t)512 * 256 * 2);
    unsigned short* Wbqkv = (unsigned short*)alloc((size_t)1536 * 512 * 2);
    unsigned short* Wbo   = (unsigned short*)alloc((size_t)512 * 512 * 2);
    unsigned short* Wg1hi = (unsigned short*)alloc((size_t)512 * 512 * 2);
    unsigned short* Wg1lo = (unsigned short*)alloc((size_t)512 * 512 * 2);
    unsigned short* Wg2hi = (unsigned short*)alloc((size_t)512 * 512 * 2);
    unsigned short* Wg2lo = (unsigned short*)alloc((size_t)512 * 512 * 2);
    unsigned short* qb    = (unsigned short*)alloc((size_t)NN_ * 512 * 2);
    unsigned short* kb    = (unsigned short*)alloc((size_t)NN_ * 512 * 2);
    unsigned short* vT    = (unsigned short*)alloc((size_t)512 * NN_ * 2);
    unsigned short* ab    = (unsigned short*)alloc((size_t)NN_ * 512 * 2);

    // overlays
    unsigned short* hb = vT;                              // bf16 h (local branch)
    unsigned short* gb = (unsigned short*)bufC;           // g bf16 (global, pre-loop)
    unsigned short* vb = gb + (size_t)NN_ * 512;          // v bf16 (global, pre-loop)
    unsigned short* Sb = (unsigned short*)bufA;           // scores: bufA+bufB = 32MB
    unsigned short* pv = (unsigned short*)bufC;           // PV bf16 partials (16MB)

    const int R = 2048, SEGS = 8, KSEG = 8192 / SEGS;
    const int EG = (NE_ + 255) / 256;
    const float scale = 0.044194173824159216f;  // 1/sqrt(512)

    // -------- casts ---------------------------------------------------------
    auto cvtb = [&](const float* s, unsigned short* d, int n) {
        cvtb_k<<<(n/4 + 255) / 256, 256, 0, stream>>>(s, d, n / 4);
    };
    cvtb(x_A,    xbA,    NA_ * 256);
    cvtb(x_B,    xbB,    NB_ * 256);
    cvtb(W_inA,  WbinA,  512 * 256);
    cvtb(W_inB,  WbinB,  512 * 256);
    cvtb(W_in2A, Wbin2A, 512 * 256);
    cvtb(W_in2B, Wbin2B, 512 * 256);
    cvtb(Wqkv,   Wbqkv,  1536 * 512);
    cvtb(Wo,     Wbo,    512 * 512);
    csplit_k<<<(512*512/4 + 255)/256, 256, 0, stream>>>(Wg1, Wg1hi, Wg1lo, 512*512/4);
    csplit_k<<<(512*512/4 + 255)/256, 256, 0, stream>>>(Wg2, Wg2hi, Wg2lo, 512*512/4);

    // -------- CSR build -----------------------------------------------------
    hipMemsetAsync(deg, 0, NN_ * 8, stream);            // deg + cursor
    count_deg_k<<<EG, 256, 0, stream>>>(eAB, eBA, deg);
    scan_k<<<1, 256, 0, stream>>>(deg, rowst);
    fill_csr_k<<<EG, 256, 0, stream>>>(eAB, eBA, rowst, cursor, csr);

    // -------- local branch --------------------------------------------------
    mgemm_in_k<true><<<dim3(4, 64), 256, 0, stream>>>(
        xbA, xbB, WbinA, WbinB, b_inA, b_inB, qb, kb);
    mgemm3_k<<<dim3(4, 64), 256, 0, stream>>>(qb, kb, Wg1hi, Wg1lo,
                                              bufB, hb, 512, 512, 512, 512);
    node_dots_k<<<NN_/4, 256, 0, stream>>>(bufB, a_src1, a_dst1, as_, ad_);
    hipMemsetAsync(mkey, 0, NN_ * 8, stream);           // mkey + denom
    edge_pass1_k<<<EG, 256, 0, stream>>>(eAB, eBA, as_, ad_, evals, mkey);
    edge_pass2_k<<<EG, 256, 0, stream>>>(eAB, eBA, mkey, evals, denom);
    gat_agg_k<true><<<NN_/4, 256, 0, stream>>>(eAB, eBA, rowst, csr, evals, denom,
                                               hb, bg1, nullptr, qb, kb);
    mgemm3_k<<<dim3(4, 64), 256, 0, stream>>>(qb, kb, Wg2hi, Wg2lo,
                                              bufB, hb, 512, 512, 512, 512);
    node_dots_k<<<NN_/4, 256, 0, stream>>>(bufB, a_src2, a_dst2, as_, ad_);
    hipMemsetAsync(mkey, 0, NN_ * 8, stream);
    edge_pass1_k<<<EG, 256, 0, stream>>>(eAB, eBA, as_, ad_, evals, mkey);
    edge_pass2_k<<<EG, 256, 0, stream>>>(eAB, eBA, mkey, evals, denom);
    gat_agg_k<false><<<NN_/4, 256, 0, stream>>>(eAB, eBA, rowst, csr, evals, denom,
                                                hb, bg2, bufA, nullptr, nullptr);
    store_half_k<<<(NN_*512)/256, 256, 0, stream>>>(bufA, out, 0);

    // -------- global branch -------------------------------------------------
    mgemm_in_k<false><<<dim3(4, 64), 256, 0, stream>>>(
        xbA, xbB, Wbin2A, Wbin2B, b_in2A, b_in2B, gb, nullptr);
    mgemm_qkv_k<<<dim3(12, 64), 256, 0, stream>>>(gb, Wbqkv, bqkv, scale, qb, kb, vb);
    trT_k<<<dim3(8, 128), 256, 0, stream>>>(vb, vT);
    for (int c0 = 0; c0 < 8192; c0 += R) {
        mgemm_k<128,128,false,unsigned short><<<dim3(64, R/128), 256, 0, stream>>>(
            qb + (size_t)c0 * 512, kb, nullptr, Sb, 512, 512, 512, 8192);
        softmax_bf16_k<<<R, 256, 0, stream>>>(Sb);
        mgemm_pv_k<<<dim3(4, R/128, SEGS), 256, 0, stream>>>(
            Sb, vT, pv, KSEG, (size_t)R * 512);
        radd_k<<<(R*512/8 + 255)/256, 256, 0, stream>>>(
            pv, ab + (size_t)c0 * 512, R*512/8, SEGS, (size_t)R*512/8);
    }
    mgemm_k<128,128,true,float><<<dim3(4, 64), 256, 0, stream>>>(
        ab, Wbo, bo, bufC, 512, 512, 512, 512);
    store_half_k<<<(NN_*512)/256, 256, 0, stream>>>(bufC, out, 512);
}